// Round 12
// baseline (1508.593 us; speedup 1.0000x reference)
//
#include <hip/hip_runtime.h>
#include <stdint.h>

#define NB 2048
#define NW 6
#define ND 1024
#define NH 8
#define NDH 128
#define NSP 1032          // padded LDS row stride (bf16 elems) = 2064 B
#define NTOT 12582912u
#define BT 256            // threads per step-kernel block (4 waves)
#define C_DT 0.09f
#define C_COUP 0.01f
#define C_TOL 0.05f
#define C_THIGH 0.22f
#define NSTEPS 16

typedef __attribute__((ext_vector_type(8))) short short8v;   // 8 bf16 (4 VGPR)
typedef __attribute__((ext_vector_type(4))) float f32x4;     // MFMA acc

struct Flags { int apply_noise; };

__host__ __device__ __forceinline__ uint32_t rotl32(uint32_t x, uint32_t d) {
  return (x << d) | (x >> (32u - d));
}

// JAX threefry2x32 (20 rounds), matches jax/_src/prng.py
__host__ __device__ __forceinline__ void tf2x32(uint32_t k0, uint32_t k1,
                                                uint32_t x0, uint32_t x1,
                                                uint32_t& o0, uint32_t& o1) {
  const uint32_t k2 = k0 ^ k1 ^ 0x1BD11BDAu;
#define TF_R4(a,b,c,d) \
  x0 += x1; x1 = rotl32(x1,a); x1 ^= x0; \
  x0 += x1; x1 = rotl32(x1,b); x1 ^= x0; \
  x0 += x1; x1 = rotl32(x1,c); x1 ^= x0; \
  x0 += x1; x1 = rotl32(x1,d); x1 ^= x0;
  x0 += k0; x1 += k1;
  TF_R4(13u,15u,26u,6u)  x0 += k1; x1 += k2 + 1u;
  TF_R4(17u,29u,16u,24u) x0 += k2; x1 += k0 + 2u;
  TF_R4(13u,15u,26u,6u)  x0 += k0; x1 += k1 + 3u;
  TF_R4(17u,29u,16u,24u) x0 += k1; x1 += k2 + 4u;
  TF_R4(13u,15u,26u,6u)  x0 += k2; x1 += k0 + 5u;
#undef TF_R4
  o0 = x0; o1 = x1;
}

// XLA ErfInv32 (Giles) coefficients; w via fast hardware log (v_log_f32).
__device__ __forceinline__ float erfinv_fast(float x) {
  const float w = -__logf(fmaf(x, -x, 1.0f));
  const float ws = w - 2.5f;
  float ps = 2.81022636e-08f;
  ps = fmaf(ps, ws, 3.43273939e-07f);
  ps = fmaf(ps, ws, -3.5233877e-06f);
  ps = fmaf(ps, ws, -4.39150654e-06f);
  ps = fmaf(ps, ws, 0.00021858087f);
  ps = fmaf(ps, ws, -0.00125372503f);
  ps = fmaf(ps, ws, -0.00417768164f);
  ps = fmaf(ps, ws, 0.246640727f);
  ps = fmaf(ps, ws, 1.50140941f);
  if (__any(w >= 5.0f)) {                     // rare tail: full Giles big-branch
    const float wb = sqrtf(w) - 3.0f;
    float pb = -0.000200214257f;
    pb = fmaf(pb, wb, 0.000100950558f);
    pb = fmaf(pb, wb, 0.00134934322f);
    pb = fmaf(pb, wb, -0.00367342844f);
    pb = fmaf(pb, wb, 0.00573950773f);
    pb = fmaf(pb, wb, -0.0076224613f);
    pb = fmaf(pb, wb, 0.00943887047f);
    pb = fmaf(pb, wb, 1.00167406f);
    pb = fmaf(pb, wb, 2.83297682f);
    return ((w < 5.0f) ? ps : pb) * x;
  }
  return ps * x;
}

__device__ __forceinline__ float noise_z(uint32_t k0, uint32_t k1, uint32_t p) {
  // JAX threefry_partitionable: counter (hi=0, lo=p), bits = o0 ^ o1
  uint32_t o0, o1;
  tf2x32(k0, k1, 0u, p, o0, o1);
  const uint32_t bits = o0 ^ o1;
  const float f = __uint_as_float((bits >> 9) | 0x3F800000u) - 1.0f;
  const float lo = -0.99999994f;                 // nextafter(-1,0) in f32
  const float u = fmaxf(lo, fmaf(f, 2.0f, lo));
  return 1.41421356237f * erfinv_fast(u);
}

// f32 <-> bf16 (RNE)
__device__ __forceinline__ unsigned short f2bf(float f) {
  const uint32_t u = __float_as_uint(f);
  return (unsigned short)((u + 0x7FFFu + ((u >> 16) & 1u)) >> 16);
}
__device__ __forceinline__ float bf2f(unsigned short h) {
  return __uint_as_float(((uint32_t)h) << 16);
}

// Batched 6-value block reduction for BT=256 (4 waves): 36 shuffles, 2 syncs.
__device__ __forceinline__ void block_sum6(float p[NW], float* red /*[4*NW]*/) {
  #pragma unroll
  for (int w = 0; w < NW; ++w)
    #pragma unroll
    for (int off = 32; off > 0; off >>= 1) p[w] += __shfl_down(p[w], off, 64);
  const int t = threadIdx.x;
  __syncthreads();                       // protect red from previous use
  if ((t & 63) == 0) {
    #pragma unroll
    for (int w = 0; w < NW; ++w) red[(t >> 6) * NW + w] = p[w];
  }
  __syncthreads();
  #pragma unroll
  for (int w = 0; w < NW; ++w)
    p[w] = red[w] + red[NW + w] + red[2 * NW + w] + red[3 * NW + w];
}

// single-value block reduce for 256-thread trailing noise kernel
__device__ __forceinline__ float block_sum4(float v, float* red) {
  #pragma unroll
  for (int off = 32; off > 0; off >>= 1) v += __shfl_down(v, off, 64);
  const int t = threadIdx.x;
  __syncthreads();
  if ((t & 63) == 0) red[t >> 6] = v;
  __syncthreads();
  return red[0] + red[1] + red[2] + red[3];
}

__global__ void init_kernel(Flags* f, int* doneArr, float* curve) {
  const int t = threadIdx.x;
  if (t == 0) f->apply_noise = 0;
  if (t < NSTEPS) {
    doneArr[t] = 0;
    curve[t] = __int_as_float(0x7FC00000);   // NaN
  }
}

// M[h][d][e] = sum_r U[h][d][r] * V[h][r][e], bf16 (hi only) in B-fragment
// order: frag = ((h*8 + nt)*4 + ks)*64 + lane, 8 bf16 each;
// lane = (e&15) | ((d>>3)&3)<<4, j = d&7, nt = e>>4, ks = d>>5.
__global__ __launch_bounds__(128) void precompute_M(const float* __restrict__ U,
                                                    const float* __restrict__ V,
                                                    unsigned short* __restrict__ Mhi) {
  const int hd = blockIdx.x;          // h*128 + d
  const int h = hd >> 7;
  const int d = hd & 127;
  const int e = threadIdx.x;
  __shared__ float u[64];
  if (e < 64) u[e] = U[hd * 64 + e];
  __syncthreads();
  float acc = 0.0f;
  #pragma unroll
  for (int r = 0; r < 64; ++r)
    acc = fmaf(u[r], V[(h * 64 + r) * 128 + e], acc);
  const int nt = e >> 4, ks = d >> 5;
  const int lane = (e & 15) | (((d >> 3) & 3) << 4);
  const int j = d & 7;
  const size_t idx = ((((size_t)(h * 8 + nt)) * 4 + ks) * 64 + lane) * 8 + j;
  Mhi[idx] = f2bf(acc);
}

// Fused per-step kernel, bf16 LDS (15.6 KB -> 8 blocks/CU), flags computed
// in-prologue from the previous step's Tarr (no flags_kernel dispatches).
// Tarr double-buffered; doneArr[k] = D[k-1] chain maintained by block 0.
__global__ __launch_bounds__(BT, 8) void step_kernel(
    const float* __restrict__ Sin, float* __restrict__ Sout,
    const float* __restrict__ signal,
    const unsigned short* __restrict__ Mhi,
    float* __restrict__ Tarr, int* __restrict__ doneArr,
    float* __restrict__ curve,
    const int step_k, const uint32_t nk0, const uint32_t nk1) {
  __shared__ __align__(16) unsigned short xs[NW][NSP];  // 12.1 KB: x, then drift
  __shared__ __align__(16) float mh[NW][NDH];           // 3 KB
  __shared__ float red[4 * NW];
  __shared__ int   redI[8];
  __shared__ float redF[4];
  const int t = threadIdx.x;
  const int b = blockIdx.x;
  const int e0 = t << 2;              // 4 cols per thread (elementwise phases)

  // ---- phase 0: issue ALL global loads (Sin, signal, Tprev) ----
  float v[NW][4];
  float sg[NW][4];
  #pragma unroll
  for (int w = 0; w < NW; ++w) {
    const float4 a = *reinterpret_cast<const float4*>(
        Sin + (size_t)(b * NW + w) * ND + e0);
    v[w][0]=a.x; v[w][1]=a.y; v[w][2]=a.z; v[w][3]=a.w;
  }
  #pragma unroll
  for (int w = 0; w < NW; ++w) {
    const float4 a = *reinterpret_cast<const float4*>(
        signal + (size_t)(b * NW + w) * ND + e0);
    sg[w][0]=a.x; sg[w][1]=a.y; sg[w][2]=a.z; sg[w][3]=a.w;
  }

  // ---- flags from previous step's tensions (k>0) ----
  int apply = 0;
  if (step_k > 0) {
    const float* Tprev = Tarr + (size_t)((step_k - 1) & 1) * NB;
    bool aL = true, aH = false;
    float s = 0.0f;
    #pragma unroll
    for (int i = 0; i < NB / BT; ++i) {     // 8 coalesced loads
      const float T = Tprev[i * BT + t];
      aL = aL && (T < C_TOL);
      aH = aH || (T > C_THIGH);
      s += T;
    }
    #pragma unroll
    for (int off = 32; off > 0; off >>= 1) s += __shfl_down(s, off, 64);
    const int wAll = __all(aL) ? 1 : 0;
    const int wAny = __any(aH) ? 1 : 0;
    if ((t & 63) == 0) {
      redI[(t >> 6) * 2 + 0] = wAll;
      redI[(t >> 6) * 2 + 1] = wAny;
      redF[t >> 6] = s;
    }
    __syncthreads();
    const int allLow  = redI[0] & redI[2] & redI[4] & redI[6];
    const int anyHigh = redI[1] | redI[3] | redI[5] | redI[7];
    const int dprev2 = doneArr[step_k - 1];     // D[k-2]
    const int d1 = dprev2 | allLow;             // D[k-1]
    apply = (!d1 && anyHigh) ? 1 : 0;
    if (b == 0 && t == 0) {
      doneArr[step_k] = d1;                     // for step k+1
      if (!dprev2) {
        const float sT = redF[0] + redF[1] + redF[2] + redF[3];
        curve[step_k - 1] = sT * (1.0f / 2048.0f);
      }
    }
    if (d1) return;                             // frozen (uniform)
  }

  // ---- phase 1: pending noise of step k-1, stage x to LDS as bf16 ----
  if (apply) {
    float p[NW];
    #pragma unroll
    for (int w = 0; w < NW; ++w) {
      const uint32_t rowbase = (uint32_t)(b * NW + w) * ND + (uint32_t)e0;
      #pragma unroll
      for (int j = 0; j < 4; ++j)
        v[w][j] = fmaf(0.01f, noise_z(nk0, nk1, rowbase + (uint32_t)j), v[w][j]);
      p[w] = v[w][0]*v[w][0] + v[w][1]*v[w][1] + v[w][2]*v[w][2] + v[w][3]*v[w][3];
    }
    block_sum6(p, red);
    #pragma unroll
    for (int w = 0; w < NW; ++w) {
      const float inv = 1.0f / (sqrtf(p[w]) + 1e-8f);
      #pragma unroll
      for (int j = 0; j < 4; ++j) v[w][j] *= inv;
    }
  }
  #pragma unroll
  for (int w = 0; w < NW; ++w) {
    const uint32_t p0 = (uint32_t)f2bf(v[w][0]) | ((uint32_t)f2bf(v[w][1]) << 16);
    const uint32_t p1 = (uint32_t)f2bf(v[w][2]) | ((uint32_t)f2bf(v[w][3]) << 16);
    *reinterpret_cast<uint2*>(&xs[w][e0]) = make_uint2(p0, p1);
  }
  __syncthreads();

  // ---- phase 2: cross-head mean (coupling) from bf16 x ----
  for (int idx = t; idx < NW * NDH; idx += BT) {   // 3 iters
    const int w = idx >> 7, el = idx & 127;
    float s = 0.0f;
    #pragma unroll
    for (int hh = 0; hh < NH; ++hh) s += bf2f(xs[w][hh * NDH + el]);
    mh[w][el] = s * 0.125f;
  }
  __syncthreads();

  // ---- phase 3: drift via MFMA (bf16 A direct from LDS), in-place ----
  {
    const int l = t & 63, wv = t >> 6;
    const int arow = l & 15, kg = l >> 4;
    #pragma unroll 1
    for (int h2 = 0; h2 < 2; ++h2) {
      const int hh = wv * 2 + h2;
      f32x4 acc0,acc1,acc2,acc3,acc4,acc5,acc6,acc7;
      acc0=acc1=acc2=acc3=acc4=acc5=acc6=acc7=(f32x4){0.f,0.f,0.f,0.f};
      f32x4* accp[8] = {&acc0,&acc1,&acc2,&acc3,&acc4,&acc5,&acc6,&acc7};
      #pragma unroll
      for (int ks = 0; ks < 4; ++ks) {
        short8v ahi = (short8v)0;
        if (arow < NW)
          ahi = *reinterpret_cast<const short8v*>(
              &xs[arow][hh * NDH + ks * 32 + kg * 8]);
        #pragma unroll
        for (int nt = 0; nt < 8; ++nt) {
          const size_t fo = ((((size_t)(hh * 8 + nt)) * 4 + ks) * 64 + l) * 8;
          const short8v bhi = *reinterpret_cast<const short8v*>(Mhi + fo);
          *accp[nt] = __builtin_amdgcn_mfma_f32_16x16x32_bf16(ahi, bhi, *accp[nt], 0, 0, 0);
        }
      }
      // scatter drift in-place as bf16 (own-head columns only)
      #pragma unroll
      for (int nt = 0; nt < 8; ++nt) {
        const f32x4 a = *accp[nt];
        #pragma unroll
        for (int r = 0; r < 4; ++r) {
          const int row = kg * 4 + r;
          if (row < NW) xs[row][hh * NDH + nt * 16 + arow] = f2bf(a[r]);
        }
      }
    }
  }
  __syncthreads();

  // ---- phase 4: Euler step (x, signal from regs; drift bf16 from xs) ----
  float acc[NW][4];
  float p[NW];
  #pragma unroll
  for (int w = 0; w < NW; ++w) {
    const uint2 d2 = *reinterpret_cast<const uint2*>(&xs[w][e0]);
    const float4 hh = *reinterpret_cast<const float4*>(&mh[w][e0 & 127]);
    const float dvf[4] = {
        bf2f((unsigned short)(d2.x & 0xFFFFu)), bf2f((unsigned short)(d2.x >> 16)),
        bf2f((unsigned short)(d2.y & 0xFFFFu)), bf2f((unsigned short)(d2.y >> 16))};
    const float mhf[4] = {hh.x, hh.y, hh.z, hh.w};
    float s2 = 0.0f;
    #pragma unroll
    for (int j = 0; j < 4; ++j) {
      const float out = -dvf[j] + C_COUP * (mhf[j] - v[w][j]) + sg[w][j];
      acc[w][j] = fmaf(C_DT, out, v[w][j]);
      s2 = fmaf(acc[w][j], acc[w][j], s2);
    }
    p[w] = s2;
  }

  // ---- phase 5: clamp_norm (batched), write Sn, keep normed in regs ----
  block_sum6(p, red);
  #pragma unroll
  for (int w = 0; w < NW; ++w) {
    const float n = sqrtf(p[w]);
    const float scale = fminf(fmaxf(n, 1e-3f), 12.0f) / fmaxf(n, 1e-8f);
    const float inv_norm = 1.0f / (n * scale + 1e-12f);
    float4 o;
    o.x = acc[w][0]*scale; o.y = acc[w][1]*scale;
    o.z = acc[w][2]*scale; o.w = acc[w][3]*scale;
    *reinterpret_cast<float4*>(Sout + (size_t)(b * NW + w) * ND + e0) = o;
    acc[w][0]=o.x*inv_norm; acc[w][1]=o.y*inv_norm;
    acc[w][2]=o.z*inv_norm; acc[w][3]=o.w*inv_norm;
  }

  // ---- phase 6: tension from register-resident normed cols ----
  float pc[NW];
  #pragma unroll
  for (int w = 0; w < NW; ++w) pc[w] = 0.0f;
  #pragma unroll
  for (int j = 0; j < 4; ++j) {
    float md = 0.0f;
    #pragma unroll
    for (int w = 0; w < NW; ++w) md += acc[w][j];
    md *= (1.0f / 6.0f);
    #pragma unroll
    for (int w = 0; w < NW; ++w) pc[w] = fmaf(acc[w][j], md, pc[w]);
  }
  block_sum6(pc, red);

  if (t == 0) {
    const float cos_sum = pc[0]+pc[1]+pc[2]+pc[3]+pc[4]+pc[5];
    Tarr[(size_t)(step_k & 1) * NB + b] = 1.0f - cos_sum * (1.0f / 6.0f);
  }
}

// single final reduction: curve[15] + trailing-noise flag
__global__ __launch_bounds__(256) void flags_final(
    Flags* __restrict__ f, const float* __restrict__ Tprev,
    const int* __restrict__ doneArr, float* __restrict__ curve) {
  __shared__ int redI[8];
  __shared__ float redF[4];
  const int t = threadIdx.x;
  bool aL = true, aH = false;
  float s = 0.0f;
  for (int i = t; i < NB; i += 256) {
    const float T = Tprev[i];
    aL = aL && (T < C_TOL);
    aH = aH || (T > C_THIGH);
    s += T;
  }
  #pragma unroll
  for (int off = 32; off > 0; off >>= 1) s += __shfl_down(s, off, 64);
  if ((t & 63) == 0) {
    redI[(t >> 6) * 2 + 0] = __all(aL) ? 1 : 0;
    redI[(t >> 6) * 2 + 1] = __any(aH) ? 1 : 0;
    redF[t >> 6] = s;
  }
  __syncthreads();
  if (t == 0) {
    const int allLow  = redI[0] & redI[2] & redI[4] & redI[6];
    const int anyHigh = redI[1] | redI[3] | redI[5] | redI[7];
    const int dprev = doneArr[NSTEPS - 1];      // D[14]
    if (!dprev)
      curve[NSTEPS - 1] = (redF[0]+redF[1]+redF[2]+redF[3]) * (1.0f / 2048.0f);
    const int dfin = dprev | allLow;            // D[15]
    f->apply_noise = (!dfin && anyHigh) ? 1 : 0;
  }
}

// trailing noise for the final step
__global__ __launch_bounds__(256) void noise_kernel(float* __restrict__ S,
                                                    const Flags* __restrict__ flags,
                                                    const uint32_t k0, const uint32_t k1) {
  if (!flags->apply_noise) return;
  __shared__ float red[4];
  const int t = threadIdx.x;
  const uint32_t base = (uint32_t)blockIdx.x * ND + (t << 2);
  const float4 s = *reinterpret_cast<const float4*>(S + base);
  float v[4] = {s.x, s.y, s.z, s.w};
  #pragma unroll
  for (int j = 0; j < 4; ++j)
    v[j] = fmaf(0.01f, noise_z(k0, k1, base + (uint32_t)j), v[j]);
  const float p2 = v[0]*v[0] + v[1]*v[1] + v[2]*v[2] + v[3]*v[3];
  const float n2 = block_sum4(p2, red);
  const float inv = 1.0f / (sqrtf(n2) + 1e-8f);
  float4 o;
  o.x = v[0]*inv; o.y = v[1]*inv; o.z = v[2]*inv; o.w = v[3]*inv;
  *reinterpret_cast<float4*>(S + base) = o;
}

extern "C" void kernel_launch(void* const* d_in, const int* in_sizes, int n_in,
                              void* d_out, int out_size, void* d_ws, size_t ws_size,
                              hipStream_t stream) {
  const float* S0     = (const float*)d_in[0];
  const float* signal = (const float*)d_in[1];
  const float* U      = (const float*)d_in[2];
  const float* V      = (const float*)d_in[3];
  float* out   = (float*)d_out;
  float* curve = out + NTOT;
  Flags* flags   = (Flags*)d_ws;
  int*   doneArr = (int*)((char*)d_ws + 64);
  float* Tarr    = (float*)((char*)d_ws + 1024);                 // 2*2048*4 = 16 KB
  unsigned short* Mhi = (unsigned short*)((char*)d_ws + 32768);  // 256 KB

  init_kernel<<<1, 32, 0, stream>>>(flags, doneArr, curve);
  precompute_M<<<NH * NDH, 128, 0, stream>>>(U, V, Mhi);

  // fold_in(key(1), k) for k=0..15 on host: threefry((0,1), (0,k))
  uint32_t K0[NSTEPS], K1[NSTEPS];
  for (uint32_t k = 0; k < NSTEPS; ++k) tf2x32(0u, 1u, 0u, k, K0[k], K1[k]);

  for (int k = 0; k < NSTEPS; ++k) {
    // step k consumes the pending noise of step k-1 (key K[k-1])
    step_kernel<<<NB, BT, 0, stream>>>(
        k == 0 ? S0 : out, out, signal, Mhi, Tarr, doneArr, curve, k,
        k > 0 ? K0[k - 1] : 0u, k > 0 ? K1[k - 1] : 0u);
  }
  flags_final<<<1, 256, 0, stream>>>(flags, Tarr + NB, doneArr, curve);
  noise_kernel<<<NB * NW, 256, 0, stream>>>(out, flags, K0[NSTEPS - 1], K1[NSTEPS - 1]);
}

// Round 13
// 1193.639 us; speedup vs baseline: 1.2639x; 1.2639x over previous
//
#include <hip/hip_runtime.h>
#include <stdint.h>

#define NB 2048
#define NW 6
#define ND 1024
#define NH 8
#define NDH 128
#define NSP 1032          // padded LDS row stride (bf16 elems) = 2064 B
#define NTOT 12582912u
#define BT 256            // threads per step-kernel block (4 waves)
#define C_DT 0.09f
#define C_COUP 0.01f
#define C_TOL 0.05f
#define C_THIGH 0.22f
#define NSTEPS 16

typedef __attribute__((ext_vector_type(8))) short short8v;   // 8 bf16 (4 VGPR)
typedef __attribute__((ext_vector_type(4))) float f32x4;     // MFMA acc

struct Flags { int apply_noise; };

__host__ __device__ __forceinline__ uint32_t rotl32(uint32_t x, uint32_t d) {
  return (x << d) | (x >> (32u - d));
}

// JAX threefry2x32 (20 rounds), matches jax/_src/prng.py
__host__ __device__ __forceinline__ void tf2x32(uint32_t k0, uint32_t k1,
                                                uint32_t x0, uint32_t x1,
                                                uint32_t& o0, uint32_t& o1) {
  const uint32_t k2 = k0 ^ k1 ^ 0x1BD11BDAu;
#define TF_R4(a,b,c,d) \
  x0 += x1; x1 = rotl32(x1,a); x1 ^= x0; \
  x0 += x1; x1 = rotl32(x1,b); x1 ^= x0; \
  x0 += x1; x1 = rotl32(x1,c); x1 ^= x0; \
  x0 += x1; x1 = rotl32(x1,d); x1 ^= x0;
  x0 += k0; x1 += k1;
  TF_R4(13u,15u,26u,6u)  x0 += k1; x1 += k2 + 1u;
  TF_R4(17u,29u,16u,24u) x0 += k2; x1 += k0 + 2u;
  TF_R4(13u,15u,26u,6u)  x0 += k0; x1 += k1 + 3u;
  TF_R4(17u,29u,16u,24u) x0 += k1; x1 += k2 + 4u;
  TF_R4(13u,15u,26u,6u)  x0 += k2; x1 += k0 + 5u;
#undef TF_R4
  o0 = x0; o1 = x1;
}

// XLA ErfInv32 (Giles) coefficients; w via fast hardware log (v_log_f32).
__device__ __forceinline__ float erfinv_fast(float x) {
  const float w = -__logf(fmaf(x, -x, 1.0f));
  const float ws = w - 2.5f;
  float ps = 2.81022636e-08f;
  ps = fmaf(ps, ws, 3.43273939e-07f);
  ps = fmaf(ps, ws, -3.5233877e-06f);
  ps = fmaf(ps, ws, -4.39150654e-06f);
  ps = fmaf(ps, ws, 0.00021858087f);
  ps = fmaf(ps, ws, -0.00125372503f);
  ps = fmaf(ps, ws, -0.00417768164f);
  ps = fmaf(ps, ws, 0.246640727f);
  ps = fmaf(ps, ws, 1.50140941f);
  if (__any(w >= 5.0f)) {                     // rare tail: full Giles big-branch
    const float wb = sqrtf(w) - 3.0f;
    float pb = -0.000200214257f;
    pb = fmaf(pb, wb, 0.000100950558f);
    pb = fmaf(pb, wb, 0.00134934322f);
    pb = fmaf(pb, wb, -0.00367342844f);
    pb = fmaf(pb, wb, 0.00573950773f);
    pb = fmaf(pb, wb, -0.0076224613f);
    pb = fmaf(pb, wb, 0.00943887047f);
    pb = fmaf(pb, wb, 1.00167406f);
    pb = fmaf(pb, wb, 2.83297682f);
    return ((w < 5.0f) ? ps : pb) * x;
  }
  return ps * x;
}

__device__ __forceinline__ float noise_z(uint32_t k0, uint32_t k1, uint32_t p) {
  // JAX threefry_partitionable: counter (hi=0, lo=p), bits = o0 ^ o1
  uint32_t o0, o1;
  tf2x32(k0, k1, 0u, p, o0, o1);
  const uint32_t bits = o0 ^ o1;
  const float f = __uint_as_float((bits >> 9) | 0x3F800000u) - 1.0f;
  const float lo = -0.99999994f;                 // nextafter(-1,0) in f32
  const float u = fmaxf(lo, fmaf(f, 2.0f, lo));
  return 1.41421356237f * erfinv_fast(u);
}

// f32 <-> bf16 (RNE)
__device__ __forceinline__ unsigned short f2bf(float f) {
  const uint32_t u = __float_as_uint(f);
  return (unsigned short)((u + 0x7FFFu + ((u >> 16) & 1u)) >> 16);
}
__device__ __forceinline__ float bf2f(unsigned short h) {
  return __uint_as_float(((uint32_t)h) << 16);
}

// Batched 6-value block reduction for BT=256 (4 waves): 36 shuffles, 2 syncs.
__device__ __forceinline__ void block_sum6(float p[NW], float* red /*[4*NW]*/) {
  #pragma unroll
  for (int w = 0; w < NW; ++w)
    #pragma unroll
    for (int off = 32; off > 0; off >>= 1) p[w] += __shfl_down(p[w], off, 64);
  const int t = threadIdx.x;
  __syncthreads();                       // protect red from previous use
  if ((t & 63) == 0) {
    #pragma unroll
    for (int w = 0; w < NW; ++w) red[(t >> 6) * NW + w] = p[w];
  }
  __syncthreads();
  #pragma unroll
  for (int w = 0; w < NW; ++w)
    p[w] = red[w] + red[NW + w] + red[2 * NW + w] + red[3 * NW + w];
}

// single-value block reduce for 256-thread trailing noise kernel
__device__ __forceinline__ float block_sum4(float v, float* red) {
  #pragma unroll
  for (int off = 32; off > 0; off >>= 1) v += __shfl_down(v, off, 64);
  const int t = threadIdx.x;
  __syncthreads();
  if ((t & 63) == 0) red[t >> 6] = v;
  __syncthreads();
  return red[0] + red[1] + red[2] + red[3];
}

__global__ void init_kernel(Flags* f, int* doneArr, float* curve) {
  const int t = threadIdx.x;
  if (t == 0) f->apply_noise = 0;
  if (t < NSTEPS) {
    doneArr[t] = 0;
    curve[t] = __int_as_float(0x7FC00000);   // NaN
  }
}

// M[h][d][e] = sum_r U[h][d][r] * V[h][r][e], bf16 (hi only) in B-fragment
// order: frag = ((h*8 + nt)*4 + ks)*64 + lane, 8 bf16 each;
// lane = (e&15) | ((d>>3)&3)<<4, j = d&7, nt = e>>4, ks = d>>5.
__global__ __launch_bounds__(128) void precompute_M(const float* __restrict__ U,
                                                    const float* __restrict__ V,
                                                    unsigned short* __restrict__ Mhi) {
  const int hd = blockIdx.x;          // h*128 + d
  const int h = hd >> 7;
  const int d = hd & 127;
  const int e = threadIdx.x;
  __shared__ float u[64];
  if (e < 64) u[e] = U[hd * 64 + e];
  __syncthreads();
  float acc = 0.0f;
  #pragma unroll
  for (int r = 0; r < 64; ++r)
    acc = fmaf(u[r], V[(h * 64 + r) * 128 + e], acc);
  const int nt = e >> 4, ks = d >> 5;
  const int lane = (e & 15) | (((d >> 3) & 3) << 4);
  const int j = d & 7;
  const size_t idx = ((((size_t)(h * 8 + nt)) * 4 + ks) * 64 + lane) * 8 + j;
  Mhi[idx] = f2bf(acc);
}

// Fused per-step kernel: bf16 LDS (15.9 KB), flags computed in-prologue from
// the previous step's Tarr. __launch_bounds__(BT,4) — the empirically-safe
// register budget (r11: VGPR 64, no spill). (BT,8) made the allocator pick
// 32 VGPRs and spill ~190 MB/dispatch (r12); (BT,5) picked 48 and spilled
// (r10). VGPR 64 -> HW allows 8 waves/SIMD anyway; LDS 15.9 KB allows 10.
__global__ __launch_bounds__(BT, 4) void step_kernel(
    const float* __restrict__ Sin, float* __restrict__ Sout,
    const float* __restrict__ signal,
    const unsigned short* __restrict__ Mhi,
    float* __restrict__ Tarr, int* __restrict__ doneArr,
    float* __restrict__ curve,
    const int step_k, const uint32_t nk0, const uint32_t nk1) {
  __shared__ __align__(16) unsigned short xs[NW][NSP];  // 12.1 KB: x, then drift
  __shared__ __align__(16) float mh[NW][NDH];           // 3 KB
  __shared__ float red[4 * NW];
  __shared__ int   redI[8];
  __shared__ float redF[4];
  const int t = threadIdx.x;
  const int b = blockIdx.x;
  const int e0 = t << 2;              // 4 cols per thread (elementwise phases)

  // ---- phase 0: issue ALL global loads (Sin, signal, Tprev) ----
  float v[NW][4];
  float sg[NW][4];
  #pragma unroll
  for (int w = 0; w < NW; ++w) {
    const float4 a = *reinterpret_cast<const float4*>(
        Sin + (size_t)(b * NW + w) * ND + e0);
    v[w][0]=a.x; v[w][1]=a.y; v[w][2]=a.z; v[w][3]=a.w;
  }
  #pragma unroll
  for (int w = 0; w < NW; ++w) {
    const float4 a = *reinterpret_cast<const float4*>(
        signal + (size_t)(b * NW + w) * ND + e0);
    sg[w][0]=a.x; sg[w][1]=a.y; sg[w][2]=a.z; sg[w][3]=a.w;
  }

  // ---- flags from previous step's tensions (k>0) ----
  int apply = 0;
  if (step_k > 0) {
    const float* Tprev = Tarr + (size_t)((step_k - 1) & 1) * NB;
    bool aL = true, aH = false;
    float s = 0.0f;
    #pragma unroll
    for (int i = 0; i < NB / BT; ++i) {     // 8 coalesced loads
      const float T = Tprev[i * BT + t];
      aL = aL && (T < C_TOL);
      aH = aH || (T > C_THIGH);
      s += T;
    }
    #pragma unroll
    for (int off = 32; off > 0; off >>= 1) s += __shfl_down(s, off, 64);
    const int wAll = __all(aL) ? 1 : 0;
    const int wAny = __any(aH) ? 1 : 0;
    if ((t & 63) == 0) {
      redI[(t >> 6) * 2 + 0] = wAll;
      redI[(t >> 6) * 2 + 1] = wAny;
      redF[t >> 6] = s;
    }
    __syncthreads();
    const int allLow  = redI[0] & redI[2] & redI[4] & redI[6];
    const int anyHigh = redI[1] | redI[3] | redI[5] | redI[7];
    const int dprev2 = doneArr[step_k - 1];     // D[k-2]
    const int d1 = dprev2 | allLow;             // D[k-1]
    apply = (!d1 && anyHigh) ? 1 : 0;
    if (b == 0 && t == 0) {
      doneArr[step_k] = d1;                     // for step k+1
      if (!dprev2) {
        const float sT = redF[0] + redF[1] + redF[2] + redF[3];
        curve[step_k - 1] = sT * (1.0f / 2048.0f);
      }
    }
    if (d1) return;                             // frozen (uniform)
  }

  // ---- phase 1: pending noise of step k-1, stage x to LDS as bf16 ----
  if (apply) {
    float p[NW];
    #pragma unroll
    for (int w = 0; w < NW; ++w) {
      const uint32_t rowbase = (uint32_t)(b * NW + w) * ND + (uint32_t)e0;
      #pragma unroll
      for (int j = 0; j < 4; ++j)
        v[w][j] = fmaf(0.01f, noise_z(nk0, nk1, rowbase + (uint32_t)j), v[w][j]);
      p[w] = v[w][0]*v[w][0] + v[w][1]*v[w][1] + v[w][2]*v[w][2] + v[w][3]*v[w][3];
    }
    block_sum6(p, red);
    #pragma unroll
    for (int w = 0; w < NW; ++w) {
      const float inv = 1.0f / (sqrtf(p[w]) + 1e-8f);
      #pragma unroll
      for (int j = 0; j < 4; ++j) v[w][j] *= inv;
    }
  }
  #pragma unroll
  for (int w = 0; w < NW; ++w) {
    const uint32_t p0 = (uint32_t)f2bf(v[w][0]) | ((uint32_t)f2bf(v[w][1]) << 16);
    const uint32_t p1 = (uint32_t)f2bf(v[w][2]) | ((uint32_t)f2bf(v[w][3]) << 16);
    *reinterpret_cast<uint2*>(&xs[w][e0]) = make_uint2(p0, p1);
  }
  __syncthreads();

  // ---- phase 2: cross-head mean (coupling) from bf16 x ----
  for (int idx = t; idx < NW * NDH; idx += BT) {   // 3 iters
    const int w = idx >> 7, el = idx & 127;
    float s = 0.0f;
    #pragma unroll
    for (int hh = 0; hh < NH; ++hh) s += bf2f(xs[w][hh * NDH + el]);
    mh[w][el] = s * 0.125f;
  }
  __syncthreads();

  // ---- phase 3: drift via MFMA (bf16 A direct from LDS), in-place ----
  {
    const int l = t & 63, wv = t >> 6;
    const int arow = l & 15, kg = l >> 4;
    #pragma unroll 1
    for (int h2 = 0; h2 < 2; ++h2) {
      const int hh = wv * 2 + h2;
      f32x4 acc0,acc1,acc2,acc3,acc4,acc5,acc6,acc7;
      acc0=acc1=acc2=acc3=acc4=acc5=acc6=acc7=(f32x4){0.f,0.f,0.f,0.f};
      f32x4* accp[8] = {&acc0,&acc1,&acc2,&acc3,&acc4,&acc5,&acc6,&acc7};
      #pragma unroll
      for (int ks = 0; ks < 4; ++ks) {
        short8v ahi = (short8v)0;
        if (arow < NW)
          ahi = *reinterpret_cast<const short8v*>(
              &xs[arow][hh * NDH + ks * 32 + kg * 8]);
        #pragma unroll
        for (int nt = 0; nt < 8; ++nt) {
          const size_t fo = ((((size_t)(hh * 8 + nt)) * 4 + ks) * 64 + l) * 8;
          const short8v bhi = *reinterpret_cast<const short8v*>(Mhi + fo);
          *accp[nt] = __builtin_amdgcn_mfma_f32_16x16x32_bf16(ahi, bhi, *accp[nt], 0, 0, 0);
        }
      }
      // scatter drift in-place as bf16 (own-head columns only)
      #pragma unroll
      for (int nt = 0; nt < 8; ++nt) {
        const f32x4 a = *accp[nt];
        #pragma unroll
        for (int r = 0; r < 4; ++r) {
          const int row = kg * 4 + r;
          if (row < NW) xs[row][hh * NDH + nt * 16 + arow] = f2bf(a[r]);
        }
      }
    }
  }
  __syncthreads();

  // ---- phase 4: Euler step (x, signal from regs; drift bf16 from xs) ----
  float acc[NW][4];
  float p[NW];
  #pragma unroll
  for (int w = 0; w < NW; ++w) {
    const uint2 d2 = *reinterpret_cast<const uint2*>(&xs[w][e0]);
    const float4 hh = *reinterpret_cast<const float4*>(&mh[w][e0 & 127]);
    const float dvf[4] = {
        bf2f((unsigned short)(d2.x & 0xFFFFu)), bf2f((unsigned short)(d2.x >> 16)),
        bf2f((unsigned short)(d2.y & 0xFFFFu)), bf2f((unsigned short)(d2.y >> 16))};
    const float mhf[4] = {hh.x, hh.y, hh.z, hh.w};
    float s2 = 0.0f;
    #pragma unroll
    for (int j = 0; j < 4; ++j) {
      const float out = -dvf[j] + C_COUP * (mhf[j] - v[w][j]) + sg[w][j];
      acc[w][j] = fmaf(C_DT, out, v[w][j]);
      s2 = fmaf(acc[w][j], acc[w][j], s2);
    }
    p[w] = s2;
  }

  // ---- phase 5: clamp_norm (batched), write Sn, keep normed in regs ----
  block_sum6(p, red);
  #pragma unroll
  for (int w = 0; w < NW; ++w) {
    const float n = sqrtf(p[w]);
    const float scale = fminf(fmaxf(n, 1e-3f), 12.0f) / fmaxf(n, 1e-8f);
    const float inv_norm = 1.0f / (n * scale + 1e-12f);
    float4 o;
    o.x = acc[w][0]*scale; o.y = acc[w][1]*scale;
    o.z = acc[w][2]*scale; o.w = acc[w][3]*scale;
    *reinterpret_cast<float4*>(Sout + (size_t)(b * NW + w) * ND + e0) = o;
    acc[w][0]=o.x*inv_norm; acc[w][1]=o.y*inv_norm;
    acc[w][2]=o.z*inv_norm; acc[w][3]=o.w*inv_norm;
  }

  // ---- phase 6: tension from register-resident normed cols ----
  float pc[NW];
  #pragma unroll
  for (int w = 0; w < NW; ++w) pc[w] = 0.0f;
  #pragma unroll
  for (int j = 0; j < 4; ++j) {
    float md = 0.0f;
    #pragma unroll
    for (int w = 0; w < NW; ++w) md += acc[w][j];
    md *= (1.0f / 6.0f);
    #pragma unroll
    for (int w = 0; w < NW; ++w) pc[w] = fmaf(acc[w][j], md, pc[w]);
  }
  block_sum6(pc, red);

  if (t == 0) {
    const float cos_sum = pc[0]+pc[1]+pc[2]+pc[3]+pc[4]+pc[5];
    Tarr[(size_t)(step_k & 1) * NB + b] = 1.0f - cos_sum * (1.0f / 6.0f);
  }
}

// single final reduction: curve[15] + trailing-noise flag
__global__ __launch_bounds__(256) void flags_final(
    Flags* __restrict__ f, const float* __restrict__ Tprev,
    const int* __restrict__ doneArr, float* __restrict__ curve) {
  __shared__ int redI[8];
  __shared__ float redF[4];
  const int t = threadIdx.x;
  bool aL = true, aH = false;
  float s = 0.0f;
  for (int i = t; i < NB; i += 256) {
    const float T = Tprev[i];
    aL = aL && (T < C_TOL);
    aH = aH || (T > C_THIGH);
    s += T;
  }
  #pragma unroll
  for (int off = 32; off > 0; off >>= 1) s += __shfl_down(s, off, 64);
  if ((t & 63) == 0) {
    redI[(t >> 6) * 2 + 0] = __all(aL) ? 1 : 0;
    redI[(t >> 6) * 2 + 1] = __any(aH) ? 1 : 0;
    redF[t >> 6] = s;
  }
  __syncthreads();
  if (t == 0) {
    const int allLow  = redI[0] & redI[2] & redI[4] & redI[6];
    const int anyHigh = redI[1] | redI[3] | redI[5] | redI[7];
    const int dprev = doneArr[NSTEPS - 1];      // D[14]
    if (!dprev)
      curve[NSTEPS - 1] = (redF[0]+redF[1]+redF[2]+redF[3]) * (1.0f / 2048.0f);
    const int dfin = dprev | allLow;            // D[15]
    f->apply_noise = (!dfin && anyHigh) ? 1 : 0;
  }
}

// trailing noise for the final step
__global__ __launch_bounds__(256) void noise_kernel(float* __restrict__ S,
                                                    const Flags* __restrict__ flags,
                                                    const uint32_t k0, const uint32_t k1) {
  if (!flags->apply_noise) return;
  __shared__ float red[4];
  const int t = threadIdx.x;
  const uint32_t base = (uint32_t)blockIdx.x * ND + (t << 2);
  const float4 s = *reinterpret_cast<const float4*>(S + base);
  float v[4] = {s.x, s.y, s.z, s.w};
  #pragma unroll
  for (int j = 0; j < 4; ++j)
    v[j] = fmaf(0.01f, noise_z(k0, k1, base + (uint32_t)j), v[j]);
  const float p2 = v[0]*v[0] + v[1]*v[1] + v[2]*v[2] + v[3]*v[3];
  const float n2 = block_sum4(p2, red);
  const float inv = 1.0f / (sqrtf(n2) + 1e-8f);
  float4 o;
  o.x = v[0]*inv; o.y = v[1]*inv; o.z = v[2]*inv; o.w = v[3]*inv;
  *reinterpret_cast<float4*>(S + base) = o;
}

extern "C" void kernel_launch(void* const* d_in, const int* in_sizes, int n_in,
                              void* d_out, int out_size, void* d_ws, size_t ws_size,
                              hipStream_t stream) {
  const float* S0     = (const float*)d_in[0];
  const float* signal = (const float*)d_in[1];
  const float* U      = (const float*)d_in[2];
  const float* V      = (const float*)d_in[3];
  float* out   = (float*)d_out;
  float* curve = out + NTOT;
  Flags* flags   = (Flags*)d_ws;
  int*   doneArr = (int*)((char*)d_ws + 64);
  float* Tarr    = (float*)((char*)d_ws + 1024);                 // 2*2048*4 = 16 KB
  unsigned short* Mhi = (unsigned short*)((char*)d_ws + 32768);  // 256 KB

  init_kernel<<<1, 32, 0, stream>>>(flags, doneArr, curve);
  precompute_M<<<NH * NDH, 128, 0, stream>>>(U, V, Mhi);

  // fold_in(key(1), k) for k=0..15 on host: threefry((0,1), (0,k))
  uint32_t K0[NSTEPS], K1[NSTEPS];
  for (uint32_t k = 0; k < NSTEPS; ++k) tf2x32(0u, 1u, 0u, k, K0[k], K1[k]);

  for (int k = 0; k < NSTEPS; ++k) {
    // step k consumes the pending noise of step k-1 (key K[k-1])
    step_kernel<<<NB, BT, 0, stream>>>(
        k == 0 ? S0 : out, out, signal, Mhi, Tarr, doneArr, curve, k,
        k > 0 ? K0[k - 1] : 0u, k > 0 ? K1[k - 1] : 0u);
  }
  flags_final<<<1, 256, 0, stream>>>(flags, Tarr + NB, doneArr, curve);
  noise_kernel<<<NB * NW, 256, 0, stream>>>(out, flags, K0[NSTEPS - 1], K1[NSTEPS - 1]);
}

// Round 14
// 1190.669 us; speedup vs baseline: 1.2670x; 1.0025x over previous
//
#include <hip/hip_runtime.h>
#include <stdint.h>

#define NB 2048
#define NW 6
#define ND 1024
#define NH 8
#define NDH 128
#define NSP 1032          // padded LDS row stride (bf16 elems) = 2064 B
#define NTOT 12582912u
#define BT 256            // threads per step-kernel block (4 waves)
#define C_DT 0.09f
#define C_COUP 0.01f
#define C_TOL 0.05f
#define C_THIGH 0.22f
#define NSTEPS 16

typedef __attribute__((ext_vector_type(8))) short short8v;   // 8 bf16 (4 VGPR)
typedef __attribute__((ext_vector_type(4))) float f32x4;     // MFMA acc

struct Flags {
  int done; int apply_noise;
};

__host__ __device__ __forceinline__ uint32_t rotl32(uint32_t x, uint32_t d) {
  return (x << d) | (x >> (32u - d));
}

// JAX threefry2x32 (20 rounds), matches jax/_src/prng.py
__host__ __device__ __forceinline__ void tf2x32(uint32_t k0, uint32_t k1,
                                                uint32_t x0, uint32_t x1,
                                                uint32_t& o0, uint32_t& o1) {
  const uint32_t k2 = k0 ^ k1 ^ 0x1BD11BDAu;
#define TF_R4(a,b,c,d) \
  x0 += x1; x1 = rotl32(x1,a); x1 ^= x0; \
  x0 += x1; x1 = rotl32(x1,b); x1 ^= x0; \
  x0 += x1; x1 = rotl32(x1,c); x1 ^= x0; \
  x0 += x1; x1 = rotl32(x1,d); x1 ^= x0;
  x0 += k0; x1 += k1;
  TF_R4(13u,15u,26u,6u)  x0 += k1; x1 += k2 + 1u;
  TF_R4(17u,29u,16u,24u) x0 += k2; x1 += k0 + 2u;
  TF_R4(13u,15u,26u,6u)  x0 += k0; x1 += k1 + 3u;
  TF_R4(17u,29u,16u,24u) x0 += k1; x1 += k2 + 4u;
  TF_R4(13u,15u,26u,6u)  x0 += k2; x1 += k0 + 5u;
#undef TF_R4
  o0 = x0; o1 = x1;
}

// XLA ErfInv32 (Giles) coefficients; w via fast hardware log (v_log_f32).
__device__ __forceinline__ float erfinv_fast(float x) {
  const float w = -__logf(fmaf(x, -x, 1.0f));
  const float ws = w - 2.5f;
  float ps = 2.81022636e-08f;
  ps = fmaf(ps, ws, 3.43273939e-07f);
  ps = fmaf(ps, ws, -3.5233877e-06f);
  ps = fmaf(ps, ws, -4.39150654e-06f);
  ps = fmaf(ps, ws, 0.00021858087f);
  ps = fmaf(ps, ws, -0.00125372503f);
  ps = fmaf(ps, ws, -0.00417768164f);
  ps = fmaf(ps, ws, 0.246640727f);
  ps = fmaf(ps, ws, 1.50140941f);
  if (__any(w >= 5.0f)) {                     // rare tail: full Giles big-branch
    const float wb = sqrtf(w) - 3.0f;
    float pb = -0.000200214257f;
    pb = fmaf(pb, wb, 0.000100950558f);
    pb = fmaf(pb, wb, 0.00134934322f);
    pb = fmaf(pb, wb, -0.00367342844f);
    pb = fmaf(pb, wb, 0.00573950773f);
    pb = fmaf(pb, wb, -0.0076224613f);
    pb = fmaf(pb, wb, 0.00943887047f);
    pb = fmaf(pb, wb, 1.00167406f);
    pb = fmaf(pb, wb, 2.83297682f);
    return ((w < 5.0f) ? ps : pb) * x;
  }
  return ps * x;
}

__device__ __forceinline__ float noise_z(uint32_t k0, uint32_t k1, uint32_t p) {
  // JAX threefry_partitionable: counter (hi=0, lo=p), bits = o0 ^ o1
  uint32_t o0, o1;
  tf2x32(k0, k1, 0u, p, o0, o1);
  const uint32_t bits = o0 ^ o1;
  const float f = __uint_as_float((bits >> 9) | 0x3F800000u) - 1.0f;
  const float lo = -0.99999994f;                 // nextafter(-1,0) in f32
  const float u = fmaxf(lo, fmaf(f, 2.0f, lo));
  return 1.41421356237f * erfinv_fast(u);
}

// f32 <-> bf16 (RNE)
__device__ __forceinline__ unsigned short f2bf(float f) {
  const uint32_t u = __float_as_uint(f);
  return (unsigned short)((u + 0x7FFFu + ((u >> 16) & 1u)) >> 16);
}
__device__ __forceinline__ float bf2f(unsigned short h) {
  return __uint_as_float(((uint32_t)h) << 16);
}

// Batched 6-value block reduction for BT=256 (4 waves): 36 shuffles, 2 syncs.
__device__ __forceinline__ void block_sum6(float p[NW], float* red /*[4*NW]*/) {
  #pragma unroll
  for (int w = 0; w < NW; ++w)
    #pragma unroll
    for (int off = 32; off > 0; off >>= 1) p[w] += __shfl_down(p[w], off, 64);
  const int t = threadIdx.x;
  __syncthreads();                       // protect red from previous use
  if ((t & 63) == 0) {
    #pragma unroll
    for (int w = 0; w < NW; ++w) red[(t >> 6) * NW + w] = p[w];
  }
  __syncthreads();
  #pragma unroll
  for (int w = 0; w < NW; ++w)
    p[w] = red[w] + red[NW + w] + red[2 * NW + w] + red[3 * NW + w];
}

// single-value block reduce for 256-thread trailing noise kernel
__device__ __forceinline__ float block_sum4(float v, float* red) {
  #pragma unroll
  for (int off = 32; off > 0; off >>= 1) v += __shfl_down(v, off, 64);
  const int t = threadIdx.x;
  __syncthreads();
  if ((t & 63) == 0) red[t >> 6] = v;
  __syncthreads();
  return red[0] + red[1] + red[2] + red[3];
}

__global__ void init_kernel(Flags* f, float* curve) {
  const int t = threadIdx.x;
  if (t == 0) { f->done = 0; f->apply_noise = 0; }
  if (t < NSTEPS) curve[t] = __int_as_float(0x7FC00000);   // NaN
}

// M[h][d][e] = sum_r U[h][d][r] * V[h][r][e], bf16 (hi only) in B-fragment
// order: frag = ((h*8 + nt)*4 + ks)*64 + lane, 8 bf16 each;
// lane = (e&15) | ((d>>3)&3)<<4, j = d&7, nt = e>>4, ks = d>>5.
__global__ __launch_bounds__(128) void precompute_M(const float* __restrict__ U,
                                                    const float* __restrict__ V,
                                                    unsigned short* __restrict__ Mhi) {
  const int hd = blockIdx.x;          // h*128 + d
  const int h = hd >> 7;
  const int d = hd & 127;
  const int e = threadIdx.x;
  __shared__ float u[64];
  if (e < 64) u[e] = U[hd * 64 + e];
  __syncthreads();
  float acc = 0.0f;
  #pragma unroll
  for (int r = 0; r < 64; ++r)
    acc = fmaf(u[r], V[(h * 64 + r) * 128 + e], acc);
  const int nt = e >> 4, ks = d >> 5;
  const int lane = (e & 15) | (((d >> 3) & 3) << 4);
  const int j = d & 7;
  const size_t idx = ((((size_t)(h * 8 + nt)) * 4 + ks) * 64 + lane) * 8 + j;
  Mhi[idx] = f2bf(acc);
}

// Fused per-step kernel: bf16 LDS (15.9 KB), separate flags_kernel (r11's
// proven control flow — folding flags into the prologue cost 16 MB/step of
// Tprev fetch plus register spill, r13). bf16 A-frags are read directly
// from LDS by the MFMA (deletes r11's 64 per-thread f2bf conversions).
// __launch_bounds__(BT,4): the empirically-safe register budget — VGPR 64,
// no spill (r11); (BT,5)/(BT,8) forced 48/32 VGPRs and catastrophic spill.
__global__ __launch_bounds__(BT, 4) void step_kernel(
    const float* __restrict__ Sin, float* __restrict__ Sout,
    const float* __restrict__ signal,
    const unsigned short* __restrict__ Mhi,
    const Flags* __restrict__ flags, float* __restrict__ Tarr,
    const uint32_t nk0, const uint32_t nk1, const int has_noise) {
  if (flags->done) return;
  __shared__ __align__(16) unsigned short xs[NW][NSP];  // 12.1 KB: x, then drift
  __shared__ __align__(16) float mh[NW][NDH];           // 3 KB
  __shared__ float red[4 * NW];
  const int t = threadIdx.x;
  const int b = blockIdx.x;
  const int e0 = t << 2;              // 4 cols per thread (elementwise phases)

  // ---- phase 0: issue Sin AND signal loads together (max MLP) ----
  float v[NW][4];
  float sg[NW][4];
  #pragma unroll
  for (int w = 0; w < NW; ++w) {
    const float4 a = *reinterpret_cast<const float4*>(
        Sin + (size_t)(b * NW + w) * ND + e0);
    v[w][0]=a.x; v[w][1]=a.y; v[w][2]=a.z; v[w][3]=a.w;
  }
  #pragma unroll
  for (int w = 0; w < NW; ++w) {
    const float4 a = *reinterpret_cast<const float4*>(
        signal + (size_t)(b * NW + w) * ND + e0);
    sg[w][0]=a.x; sg[w][1]=a.y; sg[w][2]=a.z; sg[w][3]=a.w;
  }

  // ---- phase 1: pending noise of step k-1, stage x to LDS as bf16 ----
  if (has_noise && flags->apply_noise) {
    float p[NW];
    #pragma unroll
    for (int w = 0; w < NW; ++w) {
      const uint32_t rowbase = (uint32_t)(b * NW + w) * ND + (uint32_t)e0;
      #pragma unroll
      for (int j = 0; j < 4; ++j)
        v[w][j] = fmaf(0.01f, noise_z(nk0, nk1, rowbase + (uint32_t)j), v[w][j]);
      p[w] = v[w][0]*v[w][0] + v[w][1]*v[w][1] + v[w][2]*v[w][2] + v[w][3]*v[w][3];
    }
    block_sum6(p, red);
    #pragma unroll
    for (int w = 0; w < NW; ++w) {
      const float inv = 1.0f / (sqrtf(p[w]) + 1e-8f);
      #pragma unroll
      for (int j = 0; j < 4; ++j) v[w][j] *= inv;
    }
  }
  #pragma unroll
  for (int w = 0; w < NW; ++w) {
    const uint32_t p0 = (uint32_t)f2bf(v[w][0]) | ((uint32_t)f2bf(v[w][1]) << 16);
    const uint32_t p1 = (uint32_t)f2bf(v[w][2]) | ((uint32_t)f2bf(v[w][3]) << 16);
    *reinterpret_cast<uint2*>(&xs[w][e0]) = make_uint2(p0, p1);
  }
  __syncthreads();

  // ---- phase 2: cross-head mean (coupling) from bf16 x ----
  for (int idx = t; idx < NW * NDH; idx += BT) {   // 3 iters
    const int w = idx >> 7, el = idx & 127;
    float s = 0.0f;
    #pragma unroll
    for (int hh = 0; hh < NH; ++hh) s += bf2f(xs[w][hh * NDH + el]);
    mh[w][el] = s * 0.125f;
  }
  __syncthreads();

  // ---- phase 3: drift via MFMA (bf16 A direct from LDS), in-place ----
  // wave wv owns heads 2wv,2wv+1 (exclusive column ranges -> race-free).
  {
    const int l = t & 63, wv = t >> 6;
    const int arow = l & 15, kg = l >> 4;
    #pragma unroll 1
    for (int h2 = 0; h2 < 2; ++h2) {
      const int hh = wv * 2 + h2;
      f32x4 acc0,acc1,acc2,acc3,acc4,acc5,acc6,acc7;
      acc0=acc1=acc2=acc3=acc4=acc5=acc6=acc7=(f32x4){0.f,0.f,0.f,0.f};
      f32x4* accp[8] = {&acc0,&acc1,&acc2,&acc3,&acc4,&acc5,&acc6,&acc7};
      #pragma unroll
      for (int ks = 0; ks < 4; ++ks) {
        short8v ahi = (short8v)0;
        if (arow < NW)
          ahi = *reinterpret_cast<const short8v*>(
              &xs[arow][hh * NDH + ks * 32 + kg * 8]);
        #pragma unroll
        for (int nt = 0; nt < 8; ++nt) {
          const size_t fo = ((((size_t)(hh * 8 + nt)) * 4 + ks) * 64 + l) * 8;
          const short8v bhi = *reinterpret_cast<const short8v*>(Mhi + fo);
          *accp[nt] = __builtin_amdgcn_mfma_f32_16x16x32_bf16(ahi, bhi, *accp[nt], 0, 0, 0);
        }
      }
      // scatter drift in-place as bf16 (own-head columns only)
      #pragma unroll
      for (int nt = 0; nt < 8; ++nt) {
        const f32x4 a = *accp[nt];
        #pragma unroll
        for (int r = 0; r < 4; ++r) {
          const int row = kg * 4 + r;
          if (row < NW) xs[row][hh * NDH + nt * 16 + arow] = f2bf(a[r]);
        }
      }
    }
  }
  __syncthreads();

  // ---- phase 4: Euler step (x, signal from regs; drift bf16 from xs) ----
  float acc[NW][4];
  float p[NW];
  #pragma unroll
  for (int w = 0; w < NW; ++w) {
    const uint2 d2 = *reinterpret_cast<const uint2*>(&xs[w][e0]);
    const float4 hh = *reinterpret_cast<const float4*>(&mh[w][e0 & 127]);
    const float dvf[4] = {
        bf2f((unsigned short)(d2.x & 0xFFFFu)), bf2f((unsigned short)(d2.x >> 16)),
        bf2f((unsigned short)(d2.y & 0xFFFFu)), bf2f((unsigned short)(d2.y >> 16))};
    const float mhf[4] = {hh.x, hh.y, hh.z, hh.w};
    float s2 = 0.0f;
    #pragma unroll
    for (int j = 0; j < 4; ++j) {
      const float out = -dvf[j] + C_COUP * (mhf[j] - v[w][j]) + sg[w][j];
      acc[w][j] = fmaf(C_DT, out, v[w][j]);
      s2 = fmaf(acc[w][j], acc[w][j], s2);
    }
    p[w] = s2;
  }

  // ---- phase 5: clamp_norm (batched), write Sn, keep normed in regs ----
  block_sum6(p, red);
  #pragma unroll
  for (int w = 0; w < NW; ++w) {
    const float n = sqrtf(p[w]);
    const float scale = fminf(fmaxf(n, 1e-3f), 12.0f) / fmaxf(n, 1e-8f);
    const float inv_norm = 1.0f / (n * scale + 1e-12f);
    float4 o;
    o.x = acc[w][0]*scale; o.y = acc[w][1]*scale;
    o.z = acc[w][2]*scale; o.w = acc[w][3]*scale;
    *reinterpret_cast<float4*>(Sout + (size_t)(b * NW + w) * ND + e0) = o;
    acc[w][0]=o.x*inv_norm; acc[w][1]=o.y*inv_norm;
    acc[w][2]=o.z*inv_norm; acc[w][3]=o.w*inv_norm;
  }

  // ---- phase 6: tension from register-resident normed cols ----
  float pc[NW];
  #pragma unroll
  for (int w = 0; w < NW; ++w) pc[w] = 0.0f;
  #pragma unroll
  for (int j = 0; j < 4; ++j) {
    float md = 0.0f;
    #pragma unroll
    for (int w = 0; w < NW; ++w) md += acc[w][j];
    md *= (1.0f / 6.0f);
    #pragma unroll
    for (int w = 0; w < NW; ++w) pc[w] = fmaf(acc[w][j], md, pc[w]);
  }
  block_sum6(pc, red);

  if (t == 0) {
    const float cos_sum = pc[0]+pc[1]+pc[2]+pc[3]+pc[4]+pc[5];
    Tarr[b] = 1.0f - cos_sum * (1.0f / 6.0f);     // plain store, no contention
  }
}

// 1-block reduction of Tarr -> flags + curve[k]
__global__ __launch_bounds__(256) void flags_kernel(
    Flags* __restrict__ f, const float* __restrict__ Tarr,
    float* __restrict__ curve, const int step_k) {
  __shared__ float red[12];
  const int t = threadIdx.x;
  const int done_old = f->done;
  float s = 0.0f, cl = 0.0f, ch = 0.0f;
  for (int i = t; i < NB; i += 256) {
    const float T = Tarr[i];
    s += T;
    cl += (T < C_TOL) ? 1.0f : 0.0f;
    ch += (T > C_THIGH) ? 1.0f : 0.0f;
  }
  #pragma unroll
  for (int off = 32; off > 0; off >>= 1) {
    s  += __shfl_down(s,  off, 64);
    cl += __shfl_down(cl, off, 64);
    ch += __shfl_down(ch, off, 64);
  }
  if ((t & 63) == 0) {
    red[(t >> 6) * 3 + 0] = s;
    red[(t >> 6) * 3 + 1] = cl;
    red[(t >> 6) * 3 + 2] = ch;
  }
  __syncthreads();
  if (t == 0) {
    const float sT  = red[0] + red[3] + red[6] + red[9];
    const float cln = red[1] + red[4] + red[7] + red[10];
    const float chn = red[2] + red[5] + red[8] + red[11];
    curve[step_k] = done_old ? __int_as_float(0x7FC00000) : sT * (1.0f / 2048.0f);
    const int nd = (done_old || cln == (float)NB) ? 1 : 0;
    f->apply_noise = (!nd && chn > 0.0f) ? 1 : 0;
    f->done = nd;
  }
}

// trailing noise for the final step
__global__ __launch_bounds__(256) void noise_kernel(float* __restrict__ S,
                                                    const Flags* __restrict__ flags,
                                                    const uint32_t k0, const uint32_t k1) {
  if (!flags->apply_noise) return;
  __shared__ float red[4];
  const int t = threadIdx.x;
  const uint32_t base = (uint32_t)blockIdx.x * ND + (t << 2);
  const float4 s = *reinterpret_cast<const float4*>(S + base);
  float v[4] = {s.x, s.y, s.z, s.w};
  #pragma unroll
  for (int j = 0; j < 4; ++j)
    v[j] = fmaf(0.01f, noise_z(k0, k1, base + (uint32_t)j), v[j]);
  const float p2 = v[0]*v[0] + v[1]*v[1] + v[2]*v[2] + v[3]*v[3];
  const float n2 = block_sum4(p2, red);
  const float inv = 1.0f / (sqrtf(n2) + 1e-8f);
  float4 o;
  o.x = v[0]*inv; o.y = v[1]*inv; o.z = v[2]*inv; o.w = v[3]*inv;
  *reinterpret_cast<float4*>(S + base) = o;
}

extern "C" void kernel_launch(void* const* d_in, const int* in_sizes, int n_in,
                              void* d_out, int out_size, void* d_ws, size_t ws_size,
                              hipStream_t stream) {
  const float* S0     = (const float*)d_in[0];
  const float* signal = (const float*)d_in[1];
  const float* U      = (const float*)d_in[2];
  const float* V      = (const float*)d_in[3];
  float* out   = (float*)d_out;
  float* curve = out + NTOT;
  Flags* flags = (Flags*)d_ws;
  float* Tarr  = (float*)((char*)d_ws + 512);                  // 8 KB
  unsigned short* Mhi = (unsigned short*)((char*)d_ws + 16384); // 256 KB

  init_kernel<<<1, 32, 0, stream>>>(flags, curve);
  precompute_M<<<NH * NDH, 128, 0, stream>>>(U, V, Mhi);

  // fold_in(key(1), k) for k=0..15 on host: threefry((0,1), (0,k))
  uint32_t K0[NSTEPS], K1[NSTEPS];
  for (uint32_t k = 0; k < NSTEPS; ++k) tf2x32(0u, 1u, 0u, k, K0[k], K1[k]);

  for (int k = 0; k < NSTEPS; ++k) {
    // step k consumes the pending noise of step k-1 (key K[k-1])
    step_kernel<<<NB, BT, 0, stream>>>(
        k == 0 ? S0 : out, out, signal, Mhi, flags, Tarr,
        k > 0 ? K0[k - 1] : 0u, k > 0 ? K1[k - 1] : 0u, k > 0 ? 1 : 0);
    flags_kernel<<<1, 256, 0, stream>>>(flags, Tarr, curve, k);
  }
  noise_kernel<<<NB * NW, 256, 0, stream>>>(out, flags, K0[NSTEPS - 1], K1[NSTEPS - 1]);
}

// Round 15
// 1139.837 us; speedup vs baseline: 1.3235x; 1.0446x over previous
//
#include <hip/hip_runtime.h>
#include <stdint.h>

#define NB 2048
#define NW 6
#define ND 1024
#define NH 8
#define NDH 128
#define NDP 1028          // padded LDS row stride (floats)
#define NTOT 12582912u
#define BT 256            // threads per step-kernel block (4 waves)
#define NPAIR 21          // 6x6 Gram, upper triangle incl. diagonal
#define C_DT 0.09f
#define C_COUP 0.01f
#define C_TOL 0.05f
#define C_THIGH 0.22f
#define NSTEPS 16

typedef __attribute__((ext_vector_type(8))) short short8v;   // 8 bf16 (4 VGPR)
typedef __attribute__((ext_vector_type(4))) float f32x4;     // MFMA acc

struct Flags {
  int done; int apply_noise;
};

__host__ __device__ __forceinline__ uint32_t rotl32(uint32_t x, uint32_t d) {
  return (x << d) | (x >> (32u - d));
}

// JAX threefry2x32 (20 rounds), matches jax/_src/prng.py
__host__ __device__ __forceinline__ void tf2x32(uint32_t k0, uint32_t k1,
                                                uint32_t x0, uint32_t x1,
                                                uint32_t& o0, uint32_t& o1) {
  const uint32_t k2 = k0 ^ k1 ^ 0x1BD11BDAu;
#define TF_R4(a,b,c,d) \
  x0 += x1; x1 = rotl32(x1,a); x1 ^= x0; \
  x0 += x1; x1 = rotl32(x1,b); x1 ^= x0; \
  x0 += x1; x1 = rotl32(x1,c); x1 ^= x0; \
  x0 += x1; x1 = rotl32(x1,d); x1 ^= x0;
  x0 += k0; x1 += k1;
  TF_R4(13u,15u,26u,6u)  x0 += k1; x1 += k2 + 1u;
  TF_R4(17u,29u,16u,24u) x0 += k2; x1 += k0 + 2u;
  TF_R4(13u,15u,26u,6u)  x0 += k0; x1 += k1 + 3u;
  TF_R4(17u,29u,16u,24u) x0 += k1; x1 += k2 + 4u;
  TF_R4(13u,15u,26u,6u)  x0 += k2; x1 += k0 + 5u;
#undef TF_R4
  o0 = x0; o1 = x1;
}

// XLA ErfInv32 (Giles) coefficients; w via fast hardware log (v_log_f32).
__device__ __forceinline__ float erfinv_fast(float x) {
  const float w = -__logf(fmaf(x, -x, 1.0f));
  const float ws = w - 2.5f;
  float ps = 2.81022636e-08f;
  ps = fmaf(ps, ws, 3.43273939e-07f);
  ps = fmaf(ps, ws, -3.5233877e-06f);
  ps = fmaf(ps, ws, -4.39150654e-06f);
  ps = fmaf(ps, ws, 0.00021858087f);
  ps = fmaf(ps, ws, -0.00125372503f);
  ps = fmaf(ps, ws, -0.00417768164f);
  ps = fmaf(ps, ws, 0.246640727f);
  ps = fmaf(ps, ws, 1.50140941f);
  if (__any(w >= 5.0f)) {                     // rare tail: full Giles big-branch
    const float wb = sqrtf(w) - 3.0f;
    float pb = -0.000200214257f;
    pb = fmaf(pb, wb, 0.000100950558f);
    pb = fmaf(pb, wb, 0.00134934322f);
    pb = fmaf(pb, wb, -0.00367342844f);
    pb = fmaf(pb, wb, 0.00573950773f);
    pb = fmaf(pb, wb, -0.0076224613f);
    pb = fmaf(pb, wb, 0.00943887047f);
    pb = fmaf(pb, wb, 1.00167406f);
    pb = fmaf(pb, wb, 2.83297682f);
    return ((w < 5.0f) ? ps : pb) * x;
  }
  return ps * x;
}

__device__ __forceinline__ float noise_z(uint32_t k0, uint32_t k1, uint32_t p) {
  // JAX threefry_partitionable: counter (hi=0, lo=p), bits = o0 ^ o1
  uint32_t o0, o1;
  tf2x32(k0, k1, 0u, p, o0, o1);
  const uint32_t bits = o0 ^ o1;
  const float f = __uint_as_float((bits >> 9) | 0x3F800000u) - 1.0f;
  const float lo = -0.99999994f;                 // nextafter(-1,0) in f32
  const float u = fmaxf(lo, fmaf(f, 2.0f, lo));
  return 1.41421356237f * erfinv_fast(u);
}

// f32 -> bf16 round-to-nearest-even
__device__ __forceinline__ unsigned short f2bf(float f) {
  const uint32_t u = __float_as_uint(f);
  return (unsigned short)((u + 0x7FFFu + ((u >> 16) & 1u)) >> 16);
}

// Batched 6-value block reduction for BT=256 (4 waves): 36 shuffles, 2 syncs.
__device__ __forceinline__ void block_sum6(float p[NW], float* red /*[4*NW]*/) {
  #pragma unroll
  for (int w = 0; w < NW; ++w)
    #pragma unroll
    for (int off = 32; off > 0; off >>= 1) p[w] += __shfl_down(p[w], off, 64);
  const int t = threadIdx.x;
  __syncthreads();                       // protect red from previous use
  if ((t & 63) == 0) {
    #pragma unroll
    for (int w = 0; w < NW; ++w) red[(t >> 6) * NW + w] = p[w];
  }
  __syncthreads();
  #pragma unroll
  for (int w = 0; w < NW; ++w)
    p[w] = red[w] + red[NW + w] + red[2 * NW + w] + red[3 * NW + w];
}

// Batched 21-value block reduction (Gram matrix): 126 shuffles, 2 syncs.
__device__ __forceinline__ void block_sum21(float p[NPAIR], float* red /*[4*NPAIR]*/) {
  #pragma unroll
  for (int q = 0; q < NPAIR; ++q)
    #pragma unroll
    for (int off = 32; off > 0; off >>= 1) p[q] += __shfl_down(p[q], off, 64);
  const int t = threadIdx.x;
  __syncthreads();
  if ((t & 63) == 0) {
    #pragma unroll
    for (int q = 0; q < NPAIR; ++q) red[(t >> 6) * NPAIR + q] = p[q];
  }
  __syncthreads();
  #pragma unroll
  for (int q = 0; q < NPAIR; ++q)
    p[q] = red[q] + red[NPAIR + q] + red[2 * NPAIR + q] + red[3 * NPAIR + q];
}

// single-value block reduce for 256-thread trailing noise kernel
__device__ __forceinline__ float block_sum4(float v, float* red) {
  #pragma unroll
  for (int off = 32; off > 0; off >>= 1) v += __shfl_down(v, off, 64);
  const int t = threadIdx.x;
  __syncthreads();
  if ((t & 63) == 0) red[t >> 6] = v;
  __syncthreads();
  return red[0] + red[1] + red[2] + red[3];
}

__global__ void init_kernel(Flags* f, float* curve) {
  const int t = threadIdx.x;
  if (t == 0) { f->done = 0; f->apply_noise = 0; }
  if (t < NSTEPS) curve[t] = __int_as_float(0x7FC00000);   // NaN
}

// M[h][d][e] = sum_r U[h][d][r] * V[h][r][e], bf16 (hi only) in B-fragment
// order: frag = ((h*8 + nt)*4 + ks)*64 + lane, 8 bf16 each;
// lane = (e&15) | ((d>>3)&3)<<4, j = d&7, nt = e>>4, ks = d>>5.
__global__ __launch_bounds__(128) void precompute_M(const float* __restrict__ U,
                                                    const float* __restrict__ V,
                                                    unsigned short* __restrict__ Mhi) {
  const int hd = blockIdx.x;          // h*128 + d
  const int h = hd >> 7;
  const int d = hd & 127;
  const int e = threadIdx.x;
  __shared__ float u[64];
  if (e < 64) u[e] = U[hd * 64 + e];
  __syncthreads();
  float acc = 0.0f;
  #pragma unroll
  for (int r = 0; r < 64; ++r)
    acc = fmaf(u[r], V[(h * 64 + r) * 128 + e], acc);
  const int nt = e >> 4, ks = d >> 5;
  const int lane = (e & 15) | (((d >> 3) & 3) << 4);
  const int j = d & 7;
  const size_t idx = ((((size_t)(h * 8 + nt)) * 4 + ks) * 64 + lane) * 8 + j;
  Mhi[idx] = f2bf(acc);
}

// r11 structure (best measured: f32 LDS, separate flags_kernel, (BT,4) =>
// VGPR 64 no-spill) + Gram fusion: clamp_norm and tension share ONE
// 21-value block reduction (G_wv = <Sn_w,Sn_v>; diagonal = norms^2).
// T = 1 - (1/36)*sum_{w,v} G_wv*s_w*s_v/((n_w*s_w+1e-12)(n_v*s_v+1e-12)).
__global__ __launch_bounds__(BT, 4) void step_kernel(
    const float* __restrict__ Sin, float* __restrict__ Sout,
    const float* __restrict__ signal,
    const unsigned short* __restrict__ Mhi,
    const Flags* __restrict__ flags, float* __restrict__ Tarr,
    const uint32_t nk0, const uint32_t nk1, const int has_noise) {
  if (flags->done) return;
  __shared__ __align__(16) float xs[NW][NDP];    // 24.1 KB: x, then drift in-place
  __shared__ __align__(16) float mh[NW][NDH];    // 3 KB
  __shared__ float red[4 * NPAIR];               // 336 B (also used by sum6)
  const int t = threadIdx.x;
  const int b = blockIdx.x;
  const int e0 = t << 2;              // 4 cols per thread (elementwise phases)

  // ---- phase 0: issue Sin AND signal loads together (max MLP) ----
  float v[NW][4];
  float sg[NW][4];
  #pragma unroll
  for (int w = 0; w < NW; ++w) {
    const float4 a = *reinterpret_cast<const float4*>(
        Sin + (size_t)(b * NW + w) * ND + e0);
    v[w][0]=a.x; v[w][1]=a.y; v[w][2]=a.z; v[w][3]=a.w;
  }
  #pragma unroll
  for (int w = 0; w < NW; ++w) {
    const float4 a = *reinterpret_cast<const float4*>(
        signal + (size_t)(b * NW + w) * ND + e0);
    sg[w][0]=a.x; sg[w][1]=a.y; sg[w][2]=a.z; sg[w][3]=a.w;
  }

  // ---- phase 1: pending noise of step k-1, stage x to LDS ----
  if (has_noise && flags->apply_noise) {
    float p[NW];
    #pragma unroll
    for (int w = 0; w < NW; ++w) {
      const uint32_t rowbase = (uint32_t)(b * NW + w) * ND + (uint32_t)e0;
      #pragma unroll
      for (int j = 0; j < 4; ++j)
        v[w][j] = fmaf(0.01f, noise_z(nk0, nk1, rowbase + (uint32_t)j), v[w][j]);
      p[w] = v[w][0]*v[w][0] + v[w][1]*v[w][1] + v[w][2]*v[w][2] + v[w][3]*v[w][3];
    }
    block_sum6(p, red);
    #pragma unroll
    for (int w = 0; w < NW; ++w) {
      const float inv = 1.0f / (sqrtf(p[w]) + 1e-8f);
      #pragma unroll
      for (int j = 0; j < 4; ++j) v[w][j] *= inv;
    }
  }
  #pragma unroll
  for (int w = 0; w < NW; ++w) {
    float4 a; a.x=v[w][0]; a.y=v[w][1]; a.z=v[w][2]; a.w=v[w][3];
    *reinterpret_cast<float4*>(&xs[w][e0]) = a;
  }
  __syncthreads();

  // ---- phase 2: cross-head mean (coupling) ----
  for (int idx = t; idx < NW * NDH; idx += BT) {   // 3 iters
    const int w = idx >> 7, el = idx & 127;
    float s = 0.0f;
    #pragma unroll
    for (int hh = 0; hh < NH; ++hh) s += xs[w][hh * NDH + el];
    mh[w][el] = s * 0.125f;
  }
  __syncthreads();

  // ---- phase 3: drift via MFMA (bf16-hi M), written in-place into xs ----
  // wave wv owns heads 2wv,2wv+1 (exclusive column ranges -> race-free).
  {
    const int l = t & 63, wv = t >> 6;
    const int arow = l & 15, kg = l >> 4;
    #pragma unroll 1
    for (int h2 = 0; h2 < 2; ++h2) {
      const int hh = wv * 2 + h2;
      f32x4 acc0,acc1,acc2,acc3,acc4,acc5,acc6,acc7;
      acc0=acc1=acc2=acc3=acc4=acc5=acc6=acc7=(f32x4){0.f,0.f,0.f,0.f};
      f32x4* accp[8] = {&acc0,&acc1,&acc2,&acc3,&acc4,&acc5,&acc6,&acc7};
      #pragma unroll
      for (int ks = 0; ks < 4; ++ks) {
        short8v ahi = (short8v)0;
        if (arow < NW) {
          const float* xp = &xs[arow][hh * NDH + ks * 32 + kg * 8];
          const float4 xa = *reinterpret_cast<const float4*>(xp);
          const float4 xb = *reinterpret_cast<const float4*>(xp + 4);
          const float xf[8] = {xa.x,xa.y,xa.z,xa.w,xb.x,xb.y,xb.z,xb.w};
          #pragma unroll
          for (int j = 0; j < 8; ++j) ahi[j] = (short)f2bf(xf[j]);
        }
        #pragma unroll
        for (int nt = 0; nt < 8; ++nt) {
          const size_t fo = ((((size_t)(hh * 8 + nt)) * 4 + ks) * 64 + l) * 8;
          const short8v bhi = *reinterpret_cast<const short8v*>(Mhi + fo);
          *accp[nt] = __builtin_amdgcn_mfma_f32_16x16x32_bf16(ahi, bhi, *accp[nt], 0, 0, 0);
        }
      }
      // scatter drift in-place (own-head columns only; all A-reads done)
      #pragma unroll
      for (int nt = 0; nt < 8; ++nt) {
        const f32x4 a = *accp[nt];
        #pragma unroll
        for (int r = 0; r < 4; ++r) {
          const int row = kg * 4 + r;
          if (row < NW) xs[row][hh * NDH + nt * 16 + arow] = a[r];
        }
      }
    }
  }
  __syncthreads();

  // ---- phase 4: Euler step (x, signal from regs; drift from xs) ----
  float acc[NW][4];
  #pragma unroll
  for (int w = 0; w < NW; ++w) {
    const float4 dv = *reinterpret_cast<const float4*>(&xs[w][e0]);
    const float4 hh = *reinterpret_cast<const float4*>(&mh[w][e0 & 127]);
    const float dvf[4] = {dv.x, dv.y, dv.z, dv.w};
    const float mhf[4] = {hh.x, hh.y, hh.z, hh.w};
    #pragma unroll
    for (int j = 0; j < 4; ++j) {
      const float out = -dvf[j] + C_COUP * (mhf[j] - v[w][j]) + sg[w][j];
      acc[w][j] = fmaf(C_DT, out, v[w][j]);
    }
  }

  // ---- phase 5: fused Gram reduce (norms + all pairwise dots in one go) ----
  float pr[NPAIR];
  {
    int q = 0;
    #pragma unroll
    for (int w = 0; w < NW; ++w)
      #pragma unroll
      for (int vv = w; vv < NW; ++vv) {
        float s = 0.0f;
        #pragma unroll
        for (int j = 0; j < 4; ++j) s = fmaf(acc[w][j], acc[vv][j], s);
        pr[q++] = s;
      }
  }
  block_sum21(pr, red);

  // per-w norm/scale; write Sout
  // pair index of (w,w): w*(13-w)/2 (row-major upper triangle, 6 cols)
  float nrm[NW], scl[NW];
  #pragma unroll
  for (int w = 0; w < NW; ++w) {
    const int dq = w * (13 - w) / 2;
    const float n = sqrtf(pr[dq]);
    nrm[w] = n;
    scl[w] = fminf(fmaxf(n, 1e-3f), 12.0f) / fmaxf(n, 1e-8f);
  }
  #pragma unroll
  for (int w = 0; w < NW; ++w) {
    float4 o;
    o.x = acc[w][0]*scl[w]; o.y = acc[w][1]*scl[w];
    o.z = acc[w][2]*scl[w]; o.w = acc[w][3]*scl[w];
    *reinterpret_cast<float4*>(Sout + (size_t)(b * NW + w) * ND + e0) = o;
  }

  // ---- phase 6: T from the Gram matrix (thread 0 only) ----
  if (t == 0) {
    float inv[NW];
    #pragma unroll
    for (int w = 0; w < NW; ++w) inv[w] = scl[w] / (nrm[w] * scl[w] + 1e-12f);
    float tot = 0.0f;
    int q = 0;
    #pragma unroll
    for (int w = 0; w < NW; ++w)
      #pragma unroll
      for (int vv = w; vv < NW; ++vv) {
        const float c = pr[q++] * inv[w] * inv[vv];
        tot += (vv == w) ? c : 2.0f * c;
      }
    Tarr[b] = 1.0f - tot * (1.0f / 36.0f);
  }
}

// 1-block reduction of Tarr -> flags + curve[k]
__global__ __launch_bounds__(256) void flags_kernel(
    Flags* __restrict__ f, const float* __restrict__ Tarr,
    float* __restrict__ curve, const int step_k) {
  __shared__ float red[12];
  const int t = threadIdx.x;
  const int done_old = f->done;
  float s = 0.0f, cl = 0.0f, ch = 0.0f;
  for (int i = t; i < NB; i += 256) {
    const float T = Tarr[i];
    s += T;
    cl += (T < C_TOL) ? 1.0f : 0.0f;
    ch += (T > C_THIGH) ? 1.0f : 0.0f;
  }
  #pragma unroll
  for (int off = 32; off > 0; off >>= 1) {
    s  += __shfl_down(s,  off, 64);
    cl += __shfl_down(cl, off, 64);
    ch += __shfl_down(ch, off, 64);
  }
  if ((t & 63) == 0) {
    red[(t >> 6) * 3 + 0] = s;
    red[(t >> 6) * 3 + 1] = cl;
    red[(t >> 6) * 3 + 2] = ch;
  }
  __syncthreads();
  if (t == 0) {
    const float sT  = red[0] + red[3] + red[6] + red[9];
    const float cln = red[1] + red[4] + red[7] + red[10];
    const float chn = red[2] + red[5] + red[8] + red[11];
    curve[step_k] = done_old ? __int_as_float(0x7FC00000) : sT * (1.0f / 2048.0f);
    const int nd = (done_old || cln == (float)NB) ? 1 : 0;
    f->apply_noise = (!nd && chn > 0.0f) ? 1 : 0;
    f->done = nd;
  }
}

// trailing noise for the final step
__global__ __launch_bounds__(256) void noise_kernel(float* __restrict__ S,
                                                    const Flags* __restrict__ flags,
                                                    const uint32_t k0, const uint32_t k1) {
  if (!flags->apply_noise) return;
  __shared__ float red[4];
  const int t = threadIdx.x;
  const uint32_t base = (uint32_t)blockIdx.x * ND + (t << 2);
  const float4 s = *reinterpret_cast<const float4*>(S + base);
  float v[4] = {s.x, s.y, s.z, s.w};
  #pragma unroll
  for (int j = 0; j < 4; ++j)
    v[j] = fmaf(0.01f, noise_z(k0, k1, base + (uint32_t)j), v[j]);
  const float p2 = v[0]*v[0] + v[1]*v[1] + v[2]*v[2] + v[3]*v[3];
  const float n2 = block_sum4(p2, red);
  const float inv = 1.0f / (sqrtf(n2) + 1e-8f);
  float4 o;
  o.x = v[0]*inv; o.y = v[1]*inv; o.z = v[2]*inv; o.w = v[3]*inv;
  *reinterpret_cast<float4*>(S + base) = o;
}

extern "C" void kernel_launch(void* const* d_in, const int* in_sizes, int n_in,
                              void* d_out, int out_size, void* d_ws, size_t ws_size,
                              hipStream_t stream) {
  const float* S0     = (const float*)d_in[0];
  const float* signal = (const float*)d_in[1];
  const float* U      = (const float*)d_in[2];
  const float* V      = (const float*)d_in[3];
  float* out   = (float*)d_out;
  float* curve = out + NTOT;
  Flags* flags = (Flags*)d_ws;
  float* Tarr  = (float*)((char*)d_ws + 512);                  // 8 KB
  unsigned short* Mhi = (unsigned short*)((char*)d_ws + 16384); // 256 KB

  init_kernel<<<1, 32, 0, stream>>>(flags, curve);
  precompute_M<<<NH * NDH, 128, 0, stream>>>(U, V, Mhi);

  // fold_in(key(1), k) for k=0..15 on host: threefry((0,1), (0,k))
  uint32_t K0[NSTEPS], K1[NSTEPS];
  for (uint32_t k = 0; k < NSTEPS; ++k) tf2x32(0u, 1u, 0u, k, K0[k], K1[k]);

  for (int k = 0; k < NSTEPS; ++k) {
    // step k consumes the pending noise of step k-1 (key K[k-1])
    step_kernel<<<NB, BT, 0, stream>>>(
        k == 0 ? S0 : out, out, signal, Mhi, flags, Tarr,
        k > 0 ? K0[k - 1] : 0u, k > 0 ? K1[k - 1] : 0u, k > 0 ? 1 : 0);
    flags_kernel<<<1, 256, 0, stream>>>(flags, Tarr, curve, k);
  }
  noise_kernel<<<NB * NW, 256, 0, stream>>>(out, flags, K0[NSTEPS - 1], K1[NSTEPS - 1]);
}

// Round 16
// 1094.084 us; speedup vs baseline: 1.3789x; 1.0418x over previous
//
#include <hip/hip_runtime.h>
#include <stdint.h>

#define NB 2048
#define NW 6
#define ND 1024
#define NH 8
#define NDH 128
#define NDP 1028          // padded LDS row stride (floats)
#define NTOT 12582912u
#define BT 256            // threads per step-kernel block (4 waves)
#define C_DT 0.09f
#define C_COUP 0.01f
#define C_TOL 0.05f
#define C_THIGH 0.22f
#define NSTEPS 16

typedef __attribute__((ext_vector_type(8))) short short8v;   // 8 bf16 (4 VGPR)
typedef __attribute__((ext_vector_type(4))) float f32x4;     // MFMA acc

struct Flags {
  int done; int apply_noise;
};

__host__ __device__ __forceinline__ uint32_t rotl32(uint32_t x, uint32_t d) {
  return (x << d) | (x >> (32u - d));
}

// JAX threefry2x32 (20 rounds), matches jax/_src/prng.py
__host__ __device__ __forceinline__ void tf2x32(uint32_t k0, uint32_t k1,
                                                uint32_t x0, uint32_t x1,
                                                uint32_t& o0, uint32_t& o1) {
  const uint32_t k2 = k0 ^ k1 ^ 0x1BD11BDAu;
#define TF_R4(a,b,c,d) \
  x0 += x1; x1 = rotl32(x1,a); x1 ^= x0; \
  x0 += x1; x1 = rotl32(x1,b); x1 ^= x0; \
  x0 += x1; x1 = rotl32(x1,c); x1 ^= x0; \
  x0 += x1; x1 = rotl32(x1,d); x1 ^= x0;
  x0 += k0; x1 += k1;
  TF_R4(13u,15u,26u,6u)  x0 += k1; x1 += k2 + 1u;
  TF_R4(17u,29u,16u,24u) x0 += k2; x1 += k0 + 2u;
  TF_R4(13u,15u,26u,6u)  x0 += k0; x1 += k1 + 3u;
  TF_R4(17u,29u,16u,24u) x0 += k1; x1 += k2 + 4u;
  TF_R4(13u,15u,26u,6u)  x0 += k2; x1 += k0 + 5u;
#undef TF_R4
  o0 = x0; o1 = x1;
}

// XLA ErfInv32 (Giles) coefficients; w via fast hardware log (v_log_f32).
// log1p(-x^2) -> logf(1-x^2): z error <3e-5 except ~1e-6-probability tail
// elements — all far below the 1.66e-2 threshold. pb branch taken per wave
// only when any lane has w>=5.
__device__ __forceinline__ float erfinv_fast(float x) {
  const float w = -__logf(fmaf(x, -x, 1.0f));
  const float ws = w - 2.5f;
  float ps = 2.81022636e-08f;
  ps = fmaf(ps, ws, 3.43273939e-07f);
  ps = fmaf(ps, ws, -3.5233877e-06f);
  ps = fmaf(ps, ws, -4.39150654e-06f);
  ps = fmaf(ps, ws, 0.00021858087f);
  ps = fmaf(ps, ws, -0.00125372503f);
  ps = fmaf(ps, ws, -0.00417768164f);
  ps = fmaf(ps, ws, 0.246640727f);
  ps = fmaf(ps, ws, 1.50140941f);
  if (__any(w >= 5.0f)) {                     // rare tail: full Giles big-branch
    const float wb = sqrtf(w) - 3.0f;
    float pb = -0.000200214257f;
    pb = fmaf(pb, wb, 0.000100950558f);
    pb = fmaf(pb, wb, 0.00134934322f);
    pb = fmaf(pb, wb, -0.00367342844f);
    pb = fmaf(pb, wb, 0.00573950773f);
    pb = fmaf(pb, wb, -0.0076224613f);
    pb = fmaf(pb, wb, 0.00943887047f);
    pb = fmaf(pb, wb, 1.00167406f);
    pb = fmaf(pb, wb, 2.83297682f);
    return ((w < 5.0f) ? ps : pb) * x;
  }
  return ps * x;
}

__device__ __forceinline__ float noise_z(uint32_t k0, uint32_t k1, uint32_t p) {
  // JAX threefry_partitionable: counter (hi=0, lo=p), bits = o0 ^ o1
  uint32_t o0, o1;
  tf2x32(k0, k1, 0u, p, o0, o1);
  const uint32_t bits = o0 ^ o1;
  const float f = __uint_as_float((bits >> 9) | 0x3F800000u) - 1.0f;
  const float lo = -0.99999994f;                 // nextafter(-1,0) in f32
  const float u = fmaxf(lo, fmaf(f, 2.0f, lo));
  return 1.41421356237f * erfinv_fast(u);
}

// f32 -> bf16 round-to-nearest-even
__device__ __forceinline__ unsigned short f2bf(float f) {
  const uint32_t u = __float_as_uint(f);
  return (unsigned short)((u + 0x7FFFu + ((u >> 16) & 1u)) >> 16);
}

// Batched 6-value block reduction for BT=256 (4 waves): 36 shuffles, 2 syncs.
__device__ __forceinline__ void block_sum6(float p[NW], float* red /*[4*NW]*/) {
  #pragma unroll
  for (int w = 0; w < NW; ++w)
    #pragma unroll
    for (int off = 32; off > 0; off >>= 1) p[w] += __shfl_down(p[w], off, 64);
  const int t = threadIdx.x;
  __syncthreads();                       // protect red from previous use
  if ((t & 63) == 0) {
    #pragma unroll
    for (int w = 0; w < NW; ++w) red[(t >> 6) * NW + w] = p[w];
  }
  __syncthreads();
  #pragma unroll
  for (int w = 0; w < NW; ++w)
    p[w] = red[w] + red[NW + w] + red[2 * NW + w] + red[3 * NW + w];
}

// single-value block reduce for 256-thread trailing noise kernel
__device__ __forceinline__ float block_sum4(float v, float* red) {
  #pragma unroll
  for (int off = 32; off > 0; off >>= 1) v += __shfl_down(v, off, 64);
  const int t = threadIdx.x;
  __syncthreads();
  if ((t & 63) == 0) red[t >> 6] = v;
  __syncthreads();
  return red[0] + red[1] + red[2] + red[3];
}

__global__ void init_kernel(Flags* f, float* curve) {
  const int t = threadIdx.x;
  if (t == 0) { f->done = 0; f->apply_noise = 0; }
  if (t < NSTEPS) curve[t] = __int_as_float(0x7FC00000);   // NaN
}

// M[h][d][e] = sum_r U[h][d][r] * V[h][r][e], bf16 (hi only) in B-fragment
// order: frag = ((h*8 + nt)*4 + ks)*64 + lane, 8 bf16 each;
// lane = (e&15) | ((d>>3)&3)<<4, j = d&7, nt = e>>4, ks = d>>5.
__global__ __launch_bounds__(128) void precompute_M(const float* __restrict__ U,
                                                    const float* __restrict__ V,
                                                    unsigned short* __restrict__ Mhi) {
  const int hd = blockIdx.x;          // h*128 + d
  const int h = hd >> 7;
  const int d = hd & 127;
  const int e = threadIdx.x;
  __shared__ float u[64];
  if (e < 64) u[e] = U[hd * 64 + e];
  __syncthreads();
  float acc = 0.0f;
  #pragma unroll
  for (int r = 0; r < 64; ++r)
    acc = fmaf(u[r], V[(h * 64 + r) * 128 + e], acc);
  const int nt = e >> 4, ks = d >> 5;
  const int lane = (e & 15) | (((d >> 3) & 3) << 4);
  const int j = d & 7;
  const size_t idx = ((((size_t)(h * 8 + nt)) * 4 + ks) * 64 + lane) * 8 + j;
  Mhi[idx] = f2bf(acc);
}

// Empirical-best step kernel (round 11, 1093 us total on MI355X):
// - f32 LDS staging (bf16 LDS added pack/unpack + spill, r14)
// - signal prefetched in phase 0 (doubles outstanding loads, +40% r10)
// - no atomics: T -> Tarr[b], tiny flags_kernel between steps (r10)
// - MFMA drift with bf16-hi M, written in-place into xs (r9)
// - __launch_bounds__(BT,4): VGPR 64, zero spill. (BT,5)->48 VGPR spilled
//   ~38 MB/step (r10); (BT,8)->32 VGPR spilled ~190 MB/step (r12).
__global__ __launch_bounds__(BT, 4) void step_kernel(
    const float* __restrict__ Sin, float* __restrict__ Sout,
    const float* __restrict__ signal,
    const unsigned short* __restrict__ Mhi,
    const Flags* __restrict__ flags, float* __restrict__ Tarr,
    const uint32_t nk0, const uint32_t nk1, const int has_noise) {
  if (flags->done) return;
  __shared__ __align__(16) float xs[NW][NDP];    // 24.1 KB: x, then drift in-place
  __shared__ __align__(16) float mh[NW][NDH];    // 3 KB
  __shared__ float red[4 * NW];
  const int t = threadIdx.x;
  const int b = blockIdx.x;
  const int e0 = t << 2;              // 4 cols per thread (elementwise phases)

  // ---- phase 0: issue Sin AND signal loads together (max MLP) ----
  float v[NW][4];
  float sg[NW][4];
  #pragma unroll
  for (int w = 0; w < NW; ++w) {
    const float4 a = *reinterpret_cast<const float4*>(
        Sin + (size_t)(b * NW + w) * ND + e0);
    v[w][0]=a.x; v[w][1]=a.y; v[w][2]=a.z; v[w][3]=a.w;
  }
  #pragma unroll
  for (int w = 0; w < NW; ++w) {
    const float4 a = *reinterpret_cast<const float4*>(
        signal + (size_t)(b * NW + w) * ND + e0);
    sg[w][0]=a.x; sg[w][1]=a.y; sg[w][2]=a.z; sg[w][3]=a.w;
  }
  if (has_noise && flags->apply_noise) {
    float p[NW];
    #pragma unroll
    for (int w = 0; w < NW; ++w) {
      const uint32_t rowbase = (uint32_t)(b * NW + w) * ND + (uint32_t)e0;
      #pragma unroll
      for (int j = 0; j < 4; ++j)
        v[w][j] = fmaf(0.01f, noise_z(nk0, nk1, rowbase + (uint32_t)j), v[w][j]);
      p[w] = v[w][0]*v[w][0] + v[w][1]*v[w][1] + v[w][2]*v[w][2] + v[w][3]*v[w][3];
    }
    block_sum6(p, red);
    #pragma unroll
    for (int w = 0; w < NW; ++w) {
      const float inv = 1.0f / (sqrtf(p[w]) + 1e-8f);
      #pragma unroll
      for (int j = 0; j < 4; ++j) v[w][j] *= inv;
    }
  }
  #pragma unroll
  for (int w = 0; w < NW; ++w) {
    float4 a; a.x=v[w][0]; a.y=v[w][1]; a.z=v[w][2]; a.w=v[w][3];
    *reinterpret_cast<float4*>(&xs[w][e0]) = a;
  }
  __syncthreads();

  // ---- phase 2: cross-head mean (coupling) ----
  for (int idx = t; idx < NW * NDH; idx += BT) {   // 3 iters
    const int w = idx >> 7, el = idx & 127;
    float s = 0.0f;
    #pragma unroll
    for (int hh = 0; hh < NH; ++hh) s += xs[w][hh * NDH + el];
    mh[w][el] = s * 0.125f;
  }
  __syncthreads();

  // ---- phase 3: drift via MFMA (bf16-hi M), written in-place into xs ----
  // wave wv owns heads 2wv,2wv+1 (exclusive column ranges -> race-free).
  {
    const int l = t & 63, wv = t >> 6;
    const int arow = l & 15, kg = l >> 4;
    #pragma unroll 1
    for (int h2 = 0; h2 < 2; ++h2) {
      const int hh = wv * 2 + h2;
      f32x4 acc0,acc1,acc2,acc3,acc4,acc5,acc6,acc7;
      acc0=acc1=acc2=acc3=acc4=acc5=acc6=acc7=(f32x4){0.f,0.f,0.f,0.f};
      f32x4* accp[8] = {&acc0,&acc1,&acc2,&acc3,&acc4,&acc5,&acc6,&acc7};
      #pragma unroll
      for (int ks = 0; ks < 4; ++ks) {
        short8v ahi = (short8v)0;
        if (arow < NW) {
          const float* xp = &xs[arow][hh * NDH + ks * 32 + kg * 8];
          const float4 xa = *reinterpret_cast<const float4*>(xp);
          const float4 xb = *reinterpret_cast<const float4*>(xp + 4);
          const float xf[8] = {xa.x,xa.y,xa.z,xa.w,xb.x,xb.y,xb.z,xb.w};
          #pragma unroll
          for (int j = 0; j < 8; ++j) ahi[j] = (short)f2bf(xf[j]);
        }
        #pragma unroll
        for (int nt = 0; nt < 8; ++nt) {
          const size_t fo = ((((size_t)(hh * 8 + nt)) * 4 + ks) * 64 + l) * 8;
          const short8v bhi = *reinterpret_cast<const short8v*>(Mhi + fo);
          *accp[nt] = __builtin_amdgcn_mfma_f32_16x16x32_bf16(ahi, bhi, *accp[nt], 0, 0, 0);
        }
      }
      // scatter drift in-place (own-head columns only; all A-reads done)
      #pragma unroll
      for (int nt = 0; nt < 8; ++nt) {
        const f32x4 a = *accp[nt];
        #pragma unroll
        for (int r = 0; r < 4; ++r) {
          const int row = kg * 4 + r;
          if (row < NW) xs[row][hh * NDH + nt * 16 + arow] = a[r];
        }
      }
    }
  }
  __syncthreads();

  // ---- phase 4: Euler step (x, signal from regs; drift from xs) ----
  float acc[NW][4];
  float p[NW];
  #pragma unroll
  for (int w = 0; w < NW; ++w) {
    const float4 dv = *reinterpret_cast<const float4*>(&xs[w][e0]);
    const float4 hh = *reinterpret_cast<const float4*>(&mh[w][e0 & 127]);
    const float dvf[4] = {dv.x, dv.y, dv.z, dv.w};
    const float mhf[4] = {hh.x, hh.y, hh.z, hh.w};
    float s2 = 0.0f;
    #pragma unroll
    for (int j = 0; j < 4; ++j) {
      const float out = -dvf[j] + C_COUP * (mhf[j] - v[w][j]) + sg[w][j];
      acc[w][j] = fmaf(C_DT, out, v[w][j]);
      s2 = fmaf(acc[w][j], acc[w][j], s2);
    }
    p[w] = s2;
  }

  // ---- phase 5: clamp_norm (batched), write Sn, keep normed in regs ----
  block_sum6(p, red);
  #pragma unroll
  for (int w = 0; w < NW; ++w) {
    const float n = sqrtf(p[w]);
    const float scale = fminf(fmaxf(n, 1e-3f), 12.0f) / fmaxf(n, 1e-8f);
    const float inv_norm = 1.0f / (n * scale + 1e-12f);
    float4 o;
    o.x = acc[w][0]*scale; o.y = acc[w][1]*scale;
    o.z = acc[w][2]*scale; o.w = acc[w][3]*scale;
    *reinterpret_cast<float4*>(Sout + (size_t)(b * NW + w) * ND + e0) = o;
    acc[w][0]=o.x*inv_norm; acc[w][1]=o.y*inv_norm;
    acc[w][2]=o.z*inv_norm; acc[w][3]=o.w*inv_norm;
  }

  // ---- phase 6: tension from register-resident normed cols ----
  float pc[NW];
  #pragma unroll
  for (int w = 0; w < NW; ++w) pc[w] = 0.0f;
  #pragma unroll
  for (int j = 0; j < 4; ++j) {
    float md = 0.0f;
    #pragma unroll
    for (int w = 0; w < NW; ++w) md += acc[w][j];
    md *= (1.0f / 6.0f);
    #pragma unroll
    for (int w = 0; w < NW; ++w) pc[w] = fmaf(acc[w][j], md, pc[w]);
  }
  block_sum6(pc, red);

  if (t == 0) {
    const float cos_sum = pc[0]+pc[1]+pc[2]+pc[3]+pc[4]+pc[5];
    Tarr[b] = 1.0f - cos_sum * (1.0f / 6.0f);     // plain store, no contention
  }
}

// 1-block reduction of Tarr -> flags + curve[k] (replaces all atomics)
__global__ __launch_bounds__(256) void flags_kernel(
    Flags* __restrict__ f, const float* __restrict__ Tarr,
    float* __restrict__ curve, const int step_k) {
  __shared__ float red[12];
  const int t = threadIdx.x;
  const int done_old = f->done;
  float s = 0.0f, cl = 0.0f, ch = 0.0f;
  for (int i = t; i < NB; i += 256) {
    const float T = Tarr[i];
    s += T;
    cl += (T < C_TOL) ? 1.0f : 0.0f;
    ch += (T > C_THIGH) ? 1.0f : 0.0f;
  }
  #pragma unroll
  for (int off = 32; off > 0; off >>= 1) {
    s  += __shfl_down(s,  off, 64);
    cl += __shfl_down(cl, off, 64);
    ch += __shfl_down(ch, off, 64);
  }
  if ((t & 63) == 0) {
    red[(t >> 6) * 3 + 0] = s;
    red[(t >> 6) * 3 + 1] = cl;
    red[(t >> 6) * 3 + 2] = ch;
  }
  __syncthreads();
  if (t == 0) {
    const float sT  = red[0] + red[3] + red[6] + red[9];
    const float cln = red[1] + red[4] + red[7] + red[10];
    const float chn = red[2] + red[5] + red[8] + red[11];
    curve[step_k] = done_old ? __int_as_float(0x7FC00000) : sT * (1.0f / 2048.0f);
    const int nd = (done_old || cln == (float)NB) ? 1 : 0;
    f->apply_noise = (!nd && chn > 0.0f) ? 1 : 0;
    f->done = nd;
  }
}

// trailing noise for the final step (pending noise not consumed by a next step)
__global__ __launch_bounds__(256) void noise_kernel(float* __restrict__ S,
                                                    const Flags* __restrict__ flags,
                                                    const uint32_t k0, const uint32_t k1) {
  if (!flags->apply_noise) return;
  __shared__ float red[4];
  const int t = threadIdx.x;
  const uint32_t base = (uint32_t)blockIdx.x * ND + (t << 2);
  const float4 s = *reinterpret_cast<const float4*>(S + base);
  float v[4] = {s.x, s.y, s.z, s.w};
  #pragma unroll
  for (int j = 0; j < 4; ++j)
    v[j] = fmaf(0.01f, noise_z(k0, k1, base + (uint32_t)j), v[j]);
  const float p2 = v[0]*v[0] + v[1]*v[1] + v[2]*v[2] + v[3]*v[3];
  const float n2 = block_sum4(p2, red);
  const float inv = 1.0f / (sqrtf(n2) + 1e-8f);
  float4 o;
  o.x = v[0]*inv; o.y = v[1]*inv; o.z = v[2]*inv; o.w = v[3]*inv;
  *reinterpret_cast<float4*>(S + base) = o;
}

extern "C" void kernel_launch(void* const* d_in, const int* in_sizes, int n_in,
                              void* d_out, int out_size, void* d_ws, size_t ws_size,
                              hipStream_t stream) {
  const float* S0     = (const float*)d_in[0];
  const float* signal = (const float*)d_in[1];
  const float* U      = (const float*)d_in[2];
  const float* V      = (const float*)d_in[3];
  float* out   = (float*)d_out;
  float* curve = out + NTOT;
  Flags* flags = (Flags*)d_ws;
  float* Tarr  = (float*)((char*)d_ws + 512);                  // 8 KB
  unsigned short* Mhi = (unsigned short*)((char*)d_ws + 16384); // 256 KB

  init_kernel<<<1, 32, 0, stream>>>(flags, curve);
  precompute_M<<<NH * NDH, 128, 0, stream>>>(U, V, Mhi);

  // fold_in(key(1), k) for k=0..15 on host: threefry((0,1), (0,k))
  uint32_t K0[NSTEPS], K1[NSTEPS];
  for (uint32_t k = 0; k < NSTEPS; ++k) tf2x32(0u, 1u, 0u, k, K0[k], K1[k]);

  for (int k = 0; k < NSTEPS; ++k) {
    // step k consumes the pending noise of step k-1 (key K[k-1])
    step_kernel<<<NB, BT, 0, stream>>>(
        k == 0 ? S0 : out, out, signal, Mhi, flags, Tarr,
        k > 0 ? K0[k - 1] : 0u, k > 0 ? K1[k - 1] : 0u, k > 0 ? 1 : 0);
    flags_kernel<<<1, 256, 0, stream>>>(flags, Tarr, curve, k);
  }
  noise_kernel<<<NB * NW, 256, 0, stream>>>(out, flags, K0[NSTEPS - 1], K1[NSTEPS - 1]);
}